// Round 1
// baseline (1091.012 us; speedup 1.0000x reference)
//
#include <hip/hip_runtime.h>

#define S_LEN 1024
#define DMODEL 2048
#define NH 32
#define NG 2
#define HPG 16
#define DQK 128
#define NBLK 16
#define BLKSZ 64
#define TOPN 4
#define WIN 256
#define SCALE 0.08838834764831845f

typedef float f32x4 __attribute__((ext_vector_type(4)));
typedef __bf16 bf16x8 __attribute__((ext_vector_type(8)));

__device__ __forceinline__ unsigned short f2bf(float f){
    unsigned int u = __builtin_bit_cast(unsigned int, f);
    u += 0x7fffu + ((u >> 16) & 1u);
    return (unsigned short)(u >> 16);
}
__device__ __forceinline__ float bf2f(unsigned short h){
    unsigned int u = ((unsigned int)h) << 16;
    return __builtin_bit_cast(float, u);
}

// ---------------- split convert: x -> hi bf16, lo bf16 ----------------
__global__ __launch_bounds__(256) void split_convert(
    const float* __restrict__ in, unsigned short* __restrict__ hi,
    unsigned short* __restrict__ lo, int n)
{
    int i = blockIdx.x * 256 + threadIdx.x;
    if (i < n){
        float v = in[i];
        unsigned short h = f2bf(v);
        hi[i] = h;
        lo[i] = f2bf(v - bf2f(h));
    }
}

// ---------------- transpose W[K][N] -> WT[N][K] (bf16 hi, optional lo) ----------------
__global__ __launch_bounds__(1024) void transpose_split(
    const float* __restrict__ W, unsigned short* __restrict__ WT_hi,
    unsigned short* __restrict__ WT_lo, int K, int N)
{
    __shared__ float t[32][33];
    int tx = threadIdx.x, ty = threadIdx.y;
    int k0 = blockIdx.y * 32, n0 = blockIdx.x * 32;
    int nn = n0 + tx;
    float val = 0.f;
    if (nn < N) val = W[(size_t)(k0 + ty) * N + nn];
    t[ty][tx] = val;
    __syncthreads();
    int n2 = n0 + ty;
    if (n2 < N){
        float v2 = t[tx][ty];
        unsigned short h = f2bf(v2);
        WT_hi[(size_t)n2 * K + k0 + tx] = h;
        if (WT_lo){
            WT_lo[(size_t)n2 * K + k0 + tx] = f2bf(v2 - bf2f(h));
        }
    }
}

// ---------------- bf16 MFMA GEMM: A[M][K] * BT[N][K]^T -> Co[M][N] f32 ----------------
// MODE: 0 = plain store, 1 = sigmoid.  ACC: accumulate into existing Co.
template<int MODE, bool ACC>
__global__ __launch_bounds__(256) void gemm_bf16(
    const unsigned short* __restrict__ A, const unsigned short* __restrict__ BT,
    float* __restrict__ Co, int M, int N, int K)
{
    __shared__ __align__(16) unsigned short As[64][72];
    __shared__ __align__(16) unsigned short Bs[64][72];
    const int tid = threadIdx.x;
    const int m0 = blockIdx.y * 64;
    const int n0 = blockIdx.x * 64;
    const int lane = tid & 63;
    const int w = tid >> 6;
    const int wr = w >> 1, wc = w & 1;
    f32x4 acc[2][2] = {};
    const int sr = tid >> 3;          // 0..31 staging row
    const int sc = (tid & 7) * 8;     // staging col (8 bf16 = 16B)
    for (int k0 = 0; k0 < K; k0 += 64){
        #pragma unroll
        for (int p = 0; p < 2; p++){
            int r = sr + p * 32;
            *(uint4*)(&As[r][sc]) = *(const uint4*)(&A[(size_t)(m0 + r) * K + k0 + sc]);
            int nr = n0 + r;
            uint4 bv = make_uint4(0u, 0u, 0u, 0u);
            if (nr < N) bv = *(const uint4*)(&BT[(size_t)nr * K + k0 + sc]);
            *(uint4*)(&Bs[r][sc]) = bv;
        }
        __syncthreads();
        #pragma unroll
        for (int ks = 0; ks < 2; ks++){
            bf16x8 af[2], bfr[2];
            #pragma unroll
            for (int mi = 0; mi < 2; mi++)
                af[mi] = *reinterpret_cast<const bf16x8*>(
                    &As[wr*32 + mi*16 + (lane & 15)][ks*32 + (lane >> 4)*8]);
            #pragma unroll
            for (int ni = 0; ni < 2; ni++)
                bfr[ni] = *reinterpret_cast<const bf16x8*>(
                    &Bs[wc*32 + ni*16 + (lane & 15)][ks*32 + (lane >> 4)*8]);
            #pragma unroll
            for (int mi = 0; mi < 2; mi++)
                #pragma unroll
                for (int ni = 0; ni < 2; ni++)
                    acc[mi][ni] = __builtin_amdgcn_mfma_f32_16x16x32_bf16(
                        af[mi], bfr[ni], acc[mi][ni], 0, 0, 0);
        }
        __syncthreads();
    }
    #pragma unroll
    for (int mi = 0; mi < 2; mi++)
        #pragma unroll
        for (int ni = 0; ni < 2; ni++){
            int col = n0 + wc*32 + ni*16 + (lane & 15);
            if (col < N){
                int rbase = m0 + wr*32 + mi*16 + ((lane >> 4) << 2);
                #pragma unroll
                for (int j = 0; j < 4; j++){
                    float v = acc[mi][ni][j];
                    size_t off = (size_t)(rbase + j) * N + col;
                    if (ACC) v += Co[off];
                    if (MODE == 1) v = 1.f / (1.f + expf(-v));
                    Co[off] = v;
                }
            }
        }
}

// ---------------- RoPE (in place), t: [S][nh][128] ----------------
__global__ __launch_bounds__(256) void rope_kernel(
    float* __restrict__ t, const float* __restrict__ cosb,
    const float* __restrict__ sinb, int nh, int total)
{
    int i = blockIdx.x * 256 + threadIdx.x;
    if (i >= total) return;
    int d = i & 63;
    int r = i >> 6;           // s*nh + h
    int s = r / nh;
    size_t base = (size_t)r * 128;
    float lo_v = t[base + d], hi_v = t[base + 64 + d];
    float cl = cosb[s*128 + d],      sl = sinb[s*128 + d];
    float ch = cosb[s*128 + 64 + d], sh = sinb[s*128 + 64 + d];
    t[base + d]      = lo_v * cl - hi_v * sl;
    t[base + 64 + d] = hi_v * ch + lo_v * sh;
}

// ---------------- block means: src [S][G][128] -> dst [C][G][128] ----------------
__global__ __launch_bounds__(256) void mean_blocks(
    const float* __restrict__ src, float* __restrict__ dst)
{
    int i = blockIdx.x * 256 + threadIdx.x;
    if (i >= NBLK * NG * DQK) return;
    int d = i & 127;
    int g = (i >> 7) & 1;
    int c = i >> 8;
    float s_ = 0.f;
    for (int j = 0; j < BLKSZ; j++)
        s_ += src[((size_t)(c*BLKSZ + j) * NG + g) * DQK + d];
    dst[i] = s_ * (1.f / 64.f);
}

// ---------------- compressed attention + importance + topk ----------------
__global__ __launch_bounds__(256) void cmp_attn(
    const float* __restrict__ q, const float* __restrict__ kc,
    const float* __restrict__ vc, const float* __restrict__ gates,
    float* __restrict__ o_acc, int* __restrict__ idxb)
{
    int s = blockIdx.x, g = blockIdx.y;
    __shared__ float qs[16][128];
    __shared__ float kcs[16][128];
    __shared__ float vcs[16][128];
    __shared__ float pcs[16][16];
    __shared__ float imps[16];
    int tid = threadIdx.x;
    for (int i = tid; i < 16*128; i += 256){
        int a = i >> 7, d = i & 127;
        qs[a][d]  = q[((size_t)s*NH + g*HPG + a)*DQK + d];
        kcs[a][d] = kc[((size_t)a*NG + g)*DQK + d];
        vcs[a][d] = vc[((size_t)a*NG + g)*DQK + d];
    }
    __syncthreads();
    int hh = tid >> 4, c = tid & 15;
    float acc = 0.f;
    for (int d = 0; d < 128; d++) acc += qs[hh][d] * kcs[c][d];
    acc *= SCALE;
    bool vis = ((c + 1)*BLKSZ - 1) <= s;
    float l = vis ? acc : -1e30f;
    float m = l;
    #pragma unroll
    for (int off = 1; off < 16; off <<= 1) m = fmaxf(m, __shfl_xor(m, off));
    float p = vis ? __expf(l - m) : 0.f;
    float Z = p;
    #pragma unroll
    for (int off = 1; off < 16; off <<= 1) Z += __shfl_xor(Z, off);
    p = (Z > 0.f) ? (p / Z) : 0.f;
    pcs[hh][c] = p;
    __syncthreads();
    if (tid < 16){
        float si = 0.f;
        for (int a = 0; a < 16; a++) si += pcs[a][tid];
        imps[tid] = si;
    }
    __syncthreads();
    for (int i = tid; i < HPG*DQK; i += 256){
        int h2 = i >> 7, d = i & 127;
        float o = 0.f;
        #pragma unroll
        for (int cc = 0; cc < 16; cc++) o += pcs[h2][cc] * vcs[cc][d];
        int hf = g*HPG + h2;
        o_acc[((size_t)s*NH + hf)*DQK + d] = gates[((size_t)s*NH + hf)*3 + 0] * o;
    }
    if (tid == 0){
        int cur = s >> 6;
        float sc[16];
        #pragma unroll
        for (int c2 = 0; c2 < 16; c2++){
            bool valid = (c2*BLKSZ) <= s;
            bool force = (c2 == 0) || (c2 == cur);
            sc[c2] = (valid && force) ? 1e9f : (valid ? imps[c2] : -1e9f);
        }
        int base = (s*NG + g)*TOPN;
        #pragma unroll
        for (int n = 0; n < TOPN; n++){
            float bv = -1e38f; int bi = 0;
            for (int c2 = 0; c2 < 16; c2++) if (sc[c2] > bv){ bv = sc[c2]; bi = c2; }
            idxb[base + n] = bi;
            sc[bi] = -1e38f;
        }
    }
}

// ---------------- selected attention (o_acc += g1 * o_slc) ----------------
__global__ __launch_bounds__(256) void sel_attn(
    const float* __restrict__ q, const float* __restrict__ kbuf,
    const float* __restrict__ vbuf, const float* __restrict__ gates,
    const int* __restrict__ idxb, float* __restrict__ o_acc)
{
    int s = blockIdx.x, g = blockIdx.y;
    __shared__ float qs[16][128];
    __shared__ float ps[16][256];
    __shared__ int bidx[4];
    int tid = threadIdx.x;
    if (tid < 4) bidx[tid] = idxb[(s*NG + g)*TOPN + tid];
    for (int i = tid; i < HPG*DQK; i += 256){
        int h2 = i >> 7, d = i & 127;
        qs[h2][d] = q[((size_t)s*NH + g*HPG + h2)*DQK + d];
    }
    __syncthreads();
    int pos = bidx[tid >> 6]*BLKSZ + (tid & 63);
    bool ok = (pos <= s);
    float accv[16];
    #pragma unroll
    for (int h2 = 0; h2 < 16; h2++) accv[h2] = 0.f;
    const float* krow = &kbuf[((size_t)pos*NG + g)*DQK];
    for (int d = 0; d < 128; d++){
        float kv = krow[d];
        #pragma unroll
        for (int h2 = 0; h2 < 16; h2++) accv[h2] += qs[h2][d] * kv;
    }
    #pragma unroll
    for (int h2 = 0; h2 < 16; h2++)
        ps[h2][tid] = ok ? accv[h2]*SCALE : -1e30f;
    __syncthreads();
    int hh = tid >> 4, l16 = tid & 15;
    float m = -1e30f;
    for (int i2 = l16; i2 < 256; i2 += 16) m = fmaxf(m, ps[hh][i2]);
    #pragma unroll
    for (int off = 1; off < 16; off <<= 1) m = fmaxf(m, __shfl_xor(m, off));
    float Z = 0.f;
    for (int i2 = l16; i2 < 256; i2 += 16){
        float e = __expf(ps[hh][i2] - m);
        ps[hh][i2] = e;
        Z += e;
    }
    #pragma unroll
    for (int off = 1; off < 16; off <<= 1) Z += __shfl_xor(Z, off);
    float inv = 1.f / Z;
    for (int i2 = l16; i2 < 256; i2 += 16) ps[hh][i2] *= inv;
    __syncthreads();
    for (int i = tid; i < HPG*DQK; i += 256){
        int h2 = i >> 7, d = i & 127;
        float o = 0.f;
        for (int kk2 = 0; kk2 < 256; kk2++){
            int p2 = bidx[kk2 >> 6]*BLKSZ + (kk2 & 63);
            o += ps[h2][kk2] * vbuf[((size_t)p2*NG + g)*DQK + d];
        }
        int hf = g*HPG + h2;
        size_t oo = ((size_t)s*NH + hf)*DQK + d;
        o_acc[oo] += gates[((size_t)s*NH + hf)*3 + 1] * o;
    }
}

// ---------------- window attention; writes final o as bf16 ----------------
__global__ __launch_bounds__(256) void win_attn(
    const float* __restrict__ q, const float* __restrict__ kbuf,
    const float* __restrict__ vbuf, const float* __restrict__ gates,
    const float* __restrict__ o_acc, unsigned short* __restrict__ ob)
{
    int s = blockIdx.x, g = blockIdx.y;
    __shared__ float qs[16][128];
    __shared__ float ps[16][256];
    int tid = threadIdx.x;
    for (int i = tid; i < HPG*DQK; i += 256){
        int h2 = i >> 7, d = i & 127;
        qs[h2][d] = q[((size_t)s*NH + g*HPG + h2)*DQK + d];
    }
    __syncthreads();
    int lo0 = s - (WIN - 1); if (lo0 < 0) lo0 = 0;
    int pos = lo0 + tid;
    bool ok = (pos <= s);
    int posr = ok ? pos : s;
    float accv[16];
    #pragma unroll
    for (int h2 = 0; h2 < 16; h2++) accv[h2] = 0.f;
    const float* krow = &kbuf[((size_t)posr*NG + g)*DQK];
    for (int d = 0; d < 128; d++){
        float kv = krow[d];
        #pragma unroll
        for (int h2 = 0; h2 < 16; h2++) accv[h2] += qs[h2][d] * kv;
    }
    #pragma unroll
    for (int h2 = 0; h2 < 16; h2++)
        ps[h2][tid] = ok ? accv[h2]*SCALE : -1e30f;
    __syncthreads();
    int hh = tid >> 4, l16 = tid & 15;
    float m = -1e30f;
    for (int i2 = l16; i2 < 256; i2 += 16) m = fmaxf(m, ps[hh][i2]);
    #pragma unroll
    for (int off = 1; off < 16; off <<= 1) m = fmaxf(m, __shfl_xor(m, off));
    float Z = 0.f;
    for (int i2 = l16; i2 < 256; i2 += 16){
        float e = __expf(ps[hh][i2] - m);
        ps[hh][i2] = e;
        Z += e;
    }
    #pragma unroll
    for (int off = 1; off < 16; off <<= 1) Z += __shfl_xor(Z, off);
    float inv = 1.f / Z;
    for (int i2 = l16; i2 < 256; i2 += 16) ps[hh][i2] *= inv;
    __syncthreads();
    for (int i = tid; i < HPG*DQK; i += 256){
        int h2 = i >> 7, d = i & 127;
        float o = 0.f;
        for (int kk2 = 0; kk2 < 256; kk2++){
            o += ps[h2][kk2] * vbuf[((size_t)(lo0 + kk2)*NG + g)*DQK + d];
        }
        int hf = g*HPG + h2;
        size_t oo = ((size_t)s*NH + hf)*DQK + d;
        float fin = o_acc[oo] + gates[((size_t)s*NH + hf)*3 + 2] * o;
        ob[oo] = f2bf(fin);
    }
}

extern "C" void kernel_launch(void* const* d_in, const int* in_sizes, int n_in,
                              void* d_out, int out_size, void* d_ws, size_t ws_size,
                              hipStream_t stream)
{
    (void)in_sizes; (void)n_in; (void)out_size; (void)ws_size;
    const float* x    = (const float*)d_in[0];
    const float* cosb = (const float*)d_in[1];
    const float* sinb = (const float*)d_in[2];
    const float* Wq   = (const float*)d_in[3];
    const float* Wk   = (const float*)d_in[4];
    const float* Wv   = (const float*)d_in[5];
    const float* Wo   = (const float*)d_in[6];
    const float* Wc   = (const float*)d_in[7];
    float* out = (float*)d_out;

    char* ws = (char*)d_ws;
    size_t off = 0;
    auto alloc = [&](size_t bytes)->char*{
        char* p = ws + off;
        off += (bytes + 255) & ~(size_t)255;
        return p;
    };
    unsigned short* WqT_hi = (unsigned short*)alloc(4096ull*2048*2); // later: o_acc
    unsigned short* WqT_lo = (unsigned short*)alloc(4096ull*2048*2); // later: WoT
    unsigned short* xb_hi  = (unsigned short*)alloc(1024ull*2048*2); // later: ob (spans xb_hi+xb_lo)
    unsigned short* xb_lo  = (unsigned short*)alloc(1024ull*2048*2);
    unsigned short* WkT_hi = (unsigned short*)alloc(256ull*2048*2);
    unsigned short* WkT_lo = (unsigned short*)alloc(256ull*2048*2);
    unsigned short* WvT    = (unsigned short*)alloc(256ull*2048*2);
    unsigned short* WcT    = (unsigned short*)alloc(96ull*2048*2);
    float* qbuf  = (float*)alloc(1024ull*32*128*4);
    float* kbuf  = (float*)alloc(1024ull*2*128*4);
    float* vbuf  = (float*)alloc(1024ull*2*128*4);
    float* gbuf  = (float*)alloc(1024ull*96*4);
    float* kcb   = (float*)alloc(16ull*2*128*4);
    float* vcb   = (float*)alloc(16ull*2*128*4);
    int*   idxb  = (int*)alloc(1024ull*2*4*4);
    float* o_acc = (float*)WqT_hi;            // alias (free after q GEMMs)
    unsigned short* WoT = WqT_lo;             // alias (free after q GEMMs)
    unsigned short* ob  = xb_hi;              // alias (free after gates GEMM)

    // 1. split-convert x
    split_convert<<<dim3((1024*2048)/256), 256, 0, stream>>>(x, xb_hi, xb_lo, 1024*2048);
    // 2. transpose+convert weights
    transpose_split<<<dim3(4096/32, 2048/32), dim3(32,32), 0, stream>>>(Wq, WqT_hi, WqT_lo, 2048, 4096);
    transpose_split<<<dim3(256/32, 2048/32), dim3(32,32), 0, stream>>>(Wk, WkT_hi, WkT_lo, 2048, 256);
    transpose_split<<<dim3(256/32, 2048/32), dim3(32,32), 0, stream>>>(Wv, WvT, nullptr, 2048, 256);
    transpose_split<<<dim3(3, 2048/32), dim3(32,32), 0, stream>>>(Wc, WcT, nullptr, 2048, 96);
    // 3. q = x@Wq via 3-pass split-bf16 (fp32-equivalent accuracy for topk)
    gemm_bf16<0,false><<<dim3(64,16), 256, 0, stream>>>(xb_hi, WqT_hi, qbuf, 1024, 4096, 2048);
    gemm_bf16<0,true ><<<dim3(64,16), 256, 0, stream>>>(xb_hi, WqT_lo, qbuf, 1024, 4096, 2048);
    gemm_bf16<0,true ><<<dim3(64,16), 256, 0, stream>>>(xb_lo, WqT_hi, qbuf, 1024, 4096, 2048);
    // 4. k = x@Wk (split)
    gemm_bf16<0,false><<<dim3(4,16), 256, 0, stream>>>(xb_hi, WkT_hi, kbuf, 1024, 256, 2048);
    gemm_bf16<0,true ><<<dim3(4,16), 256, 0, stream>>>(xb_hi, WkT_lo, kbuf, 1024, 256, 2048);
    gemm_bf16<0,true ><<<dim3(4,16), 256, 0, stream>>>(xb_lo, WkT_hi, kbuf, 1024, 256, 2048);
    // 5. v, gates (plain bf16)
    gemm_bf16<0,false><<<dim3(4,16), 256, 0, stream>>>(xb_hi, WvT, vbuf, 1024, 256, 2048);
    gemm_bf16<1,false><<<dim3(2,16), 256, 0, stream>>>(xb_hi, WcT, gbuf, 1024, 96, 2048);
    // 6. RoPE in place
    rope_kernel<<<dim3((1024*32*64)/256), 256, 0, stream>>>(qbuf, cosb, sinb, 32, 1024*32*64);
    rope_kernel<<<dim3((1024*2*64)/256), 256, 0, stream>>>(kbuf, cosb, sinb, 2, 1024*2*64);
    // 7. block means (kc from RoPE'd k)
    mean_blocks<<<dim3(16), 256, 0, stream>>>(kbuf, kcb);
    mean_blocks<<<dim3(16), 256, 0, stream>>>(vbuf, vcb);
    // 8. Wo transpose (WqT_lo region now free)
    transpose_split<<<dim3(2048/32, 4096/32), dim3(32,32), 0, stream>>>(Wo, WoT, nullptr, 4096, 2048);
    // 9-11. attention branches
    cmp_attn<<<dim3(1024,2), 256, 0, stream>>>(qbuf, kcb, vcb, gbuf, o_acc, idxb);
    sel_attn<<<dim3(1024,2), 256, 0, stream>>>(qbuf, kbuf, vbuf, gbuf, idxb, o_acc);
    win_attn<<<dim3(1024,2), 256, 0, stream>>>(qbuf, kbuf, vbuf, gbuf, o_acc, ob);
    // 12. out = o @ Wo
    gemm_bf16<0,false><<<dim3(32,16), 256, 0, stream>>>(ob, WoT, out, 1024, 2048, 4096);
}

// Round 2
// 685.601 us; speedup vs baseline: 1.5913x; 1.5913x over previous
//
#include <hip/hip_runtime.h>

#define S_LEN 1024
#define DMODEL 2048
#define NH 32
#define NG 2
#define HPG 16
#define DQK 128
#define NBLK 16
#define BLKSZ 64
#define TOPN 4
#define WIN 256
#define SCALE 0.08838834764831845f

typedef float f32x4 __attribute__((ext_vector_type(4)));
typedef __bf16 bf16x8 __attribute__((ext_vector_type(8)));

__device__ __forceinline__ unsigned short f2bf(float f){
    unsigned int u = __builtin_bit_cast(unsigned int, f);
    u += 0x7fffu + ((u >> 16) & 1u);
    return (unsigned short)(u >> 16);
}
__device__ __forceinline__ float bf2f(unsigned short h){
    unsigned int u = ((unsigned int)h) << 16;
    return __builtin_bit_cast(float, u);
}

// ---------------- split convert: x -> hi bf16, lo bf16 ----------------
__global__ __launch_bounds__(256) void split_convert(
    const float* __restrict__ in, unsigned short* __restrict__ hi,
    unsigned short* __restrict__ lo, int n)
{
    int i = blockIdx.x * 256 + threadIdx.x;
    if (i < n){
        float v = in[i];
        unsigned short h = f2bf(v);
        hi[i] = h;
        lo[i] = f2bf(v - bf2f(h));
    }
}

// ---------------- transpose W[K][N] -> WT[N][K] (bf16 hi, optional lo) ----------------
__global__ __launch_bounds__(1024) void transpose_split(
    const float* __restrict__ W, unsigned short* __restrict__ WT_hi,
    unsigned short* __restrict__ WT_lo, int K, int N)
{
    __shared__ float t[32][33];
    int tx = threadIdx.x, ty = threadIdx.y;
    int k0 = blockIdx.y * 32, n0 = blockIdx.x * 32;
    int nn = n0 + tx;
    float val = 0.f;
    if (nn < N) val = W[(size_t)(k0 + ty) * N + nn];
    t[ty][tx] = val;
    __syncthreads();
    int n2 = n0 + ty;
    if (n2 < N){
        float v2 = t[tx][ty];
        unsigned short h = f2bf(v2);
        WT_hi[(size_t)n2 * K + k0 + tx] = h;
        if (WT_lo){
            WT_lo[(size_t)n2 * K + k0 + tx] = f2bf(v2 - bf2f(h));
        }
    }
}

// ---------------- bf16 MFMA GEMM: A[M][K] * BT[N][K]^T -> Co[M][N] f32 ----------------
template<int MODE, bool ACC>
__global__ __launch_bounds__(256) void gemm_bf16(
    const unsigned short* __restrict__ A, const unsigned short* __restrict__ BT,
    float* __restrict__ Co, int M, int N, int K)
{
    __shared__ __align__(16) unsigned short As[64][72];
    __shared__ __align__(16) unsigned short Bs[64][72];
    const int tid = threadIdx.x;
    const int m0 = blockIdx.y * 64;
    const int n0 = blockIdx.x * 64;
    const int lane = tid & 63;
    const int w = tid >> 6;
    const int wr = w >> 1, wc = w & 1;
    f32x4 acc[2][2] = {};
    const int sr = tid >> 3;
    const int sc = (tid & 7) * 8;
    for (int k0 = 0; k0 < K; k0 += 64){
        #pragma unroll
        for (int p = 0; p < 2; p++){
            int r = sr + p * 32;
            *(uint4*)(&As[r][sc]) = *(const uint4*)(&A[(size_t)(m0 + r) * K + k0 + sc]);
            int nr = n0 + r;
            uint4 bv = make_uint4(0u, 0u, 0u, 0u);
            if (nr < N) bv = *(const uint4*)(&BT[(size_t)nr * K + k0 + sc]);
            *(uint4*)(&Bs[r][sc]) = bv;
        }
        __syncthreads();
        #pragma unroll
        for (int ks = 0; ks < 2; ks++){
            bf16x8 af[2], bfr[2];
            #pragma unroll
            for (int mi = 0; mi < 2; mi++)
                af[mi] = *reinterpret_cast<const bf16x8*>(
                    &As[wr*32 + mi*16 + (lane & 15)][ks*32 + (lane >> 4)*8]);
            #pragma unroll
            for (int ni = 0; ni < 2; ni++)
                bfr[ni] = *reinterpret_cast<const bf16x8*>(
                    &Bs[wc*32 + ni*16 + (lane & 15)][ks*32 + (lane >> 4)*8]);
            #pragma unroll
            for (int mi = 0; mi < 2; mi++)
                #pragma unroll
                for (int ni = 0; ni < 2; ni++)
                    acc[mi][ni] = __builtin_amdgcn_mfma_f32_16x16x32_bf16(
                        af[mi], bfr[ni], acc[mi][ni], 0, 0, 0);
        }
        __syncthreads();
    }
    #pragma unroll
    for (int mi = 0; mi < 2; mi++)
        #pragma unroll
        for (int ni = 0; ni < 2; ni++){
            int col = n0 + wc*32 + ni*16 + (lane & 15);
            if (col < N){
                int rbase = m0 + wr*32 + mi*16 + ((lane >> 4) << 2);
                #pragma unroll
                for (int j = 0; j < 4; j++){
                    float v = acc[mi][ni][j];
                    size_t off = (size_t)(rbase + j) * N + col;
                    if (ACC) v += Co[off];
                    if (MODE == 1) v = 1.f / (1.f + expf(-v));
                    Co[off] = v;
                }
            }
        }
}

// ---------------- RoPE (in place), t: [S][nh][128] ----------------
__global__ __launch_bounds__(256) void rope_kernel(
    float* __restrict__ t, const float* __restrict__ cosb,
    const float* __restrict__ sinb, int nh, int total)
{
    int i = blockIdx.x * 256 + threadIdx.x;
    if (i >= total) return;
    int d = i & 63;
    int r = i >> 6;
    int s = r / nh;
    size_t base = (size_t)r * 128;
    float lo_v = t[base + d], hi_v = t[base + 64 + d];
    float cl = cosb[s*128 + d],      sl = sinb[s*128 + d];
    float ch = cosb[s*128 + 64 + d], sh = sinb[s*128 + 64 + d];
    t[base + d]      = lo_v * cl - hi_v * sl;
    t[base + 64 + d] = hi_v * ch + lo_v * sh;
}

// ---------------- block means: src [S][G][128] -> dst [C][G][128] ----------------
__global__ __launch_bounds__(256) void mean_blocks(
    const float* __restrict__ src, float* __restrict__ dst)
{
    int i = blockIdx.x * 256 + threadIdx.x;
    if (i >= NBLK * NG * DQK) return;
    int d = i & 127;
    int g = (i >> 7) & 1;
    int c = i >> 8;
    float s_ = 0.f;
    for (int j = 0; j < BLKSZ; j++)
        s_ += src[((size_t)(c*BLKSZ + j) * NG + g) * DQK + d];
    dst[i] = s_ * (1.f / 64.f);
}

// ---------------- kbuf f32 -> bf16 copy ----------------
__global__ __launch_bounds__(256) void kb_convert(
    const float* __restrict__ in, unsigned short* __restrict__ out, int n4)
{
    int i = blockIdx.x * 256 + threadIdx.x;
    if (i < n4){
        f32x4 v = ((const f32x4*)in)[i];
        ushort4 o;
        o.x = f2bf(v[0]); o.y = f2bf(v[1]); o.z = f2bf(v[2]); o.w = f2bf(v[3]);
        ((ushort4*)out)[i] = o;
    }
}

// ---------------- vbuf [S][G][128] f32 -> Vt [G][128][S] bf16 ----------------
__global__ __launch_bounds__(1024) void vt_transpose(
    const float* __restrict__ v, unsigned short* __restrict__ Vt)
{
    __shared__ float t[32][33];
    int g = blockIdx.z;
    int s0 = blockIdx.x * 32, d0 = blockIdx.y * 32;
    int tx = threadIdx.x, ty = threadIdx.y;
    t[ty][tx] = v[((size_t)(s0 + ty)*NG + g)*DQK + d0 + tx];
    __syncthreads();
    Vt[((size_t)g*DQK + d0 + ty)*S_LEN + s0 + tx] = f2bf(t[tx][ty]);
}

// ---------------- compressed attention + importance + topk (fp32, padded LDS) ----------------
__global__ __launch_bounds__(256) void cmp_attn(
    const float* __restrict__ q, const float* __restrict__ kc,
    const float* __restrict__ vc, const float* __restrict__ gates,
    float* __restrict__ o_acc, int* __restrict__ idxb)
{
    int s = blockIdx.x, g = blockIdx.y;
    __shared__ float qs[16][132];
    __shared__ float kcs[16][132];
    __shared__ float vcs[16][132];
    __shared__ float pcs[16][16];
    __shared__ float imps[16];
    int tid = threadIdx.x;
    for (int i = tid; i < 16*128; i += 256){
        int a = i >> 7, d = i & 127;
        qs[a][d]  = q[((size_t)s*NH + g*HPG + a)*DQK + d];
        kcs[a][d] = kc[((size_t)a*NG + g)*DQK + d];
        vcs[a][d] = vc[((size_t)a*NG + g)*DQK + d];
    }
    __syncthreads();
    int hh = tid >> 4, c = tid & 15;
    float acc = 0.f;
    for (int d4 = 0; d4 < 128; d4 += 4){
        f32x4 qv = *(const f32x4*)&qs[hh][d4];
        f32x4 kv = *(const f32x4*)&kcs[c][d4];
        acc += qv[0]*kv[0] + qv[1]*kv[1] + qv[2]*kv[2] + qv[3]*kv[3];
    }
    acc *= SCALE;
    bool vis = ((c + 1)*BLKSZ - 1) <= s;
    float l = vis ? acc : -1e30f;
    float m = l;
    #pragma unroll
    for (int off = 1; off < 16; off <<= 1) m = fmaxf(m, __shfl_xor(m, off));
    float p = vis ? __expf(l - m) : 0.f;
    float Z = p;
    #pragma unroll
    for (int off = 1; off < 16; off <<= 1) Z += __shfl_xor(Z, off);
    p = (Z > 0.f) ? (p / Z) : 0.f;
    pcs[hh][c] = p;
    __syncthreads();
    if (tid < 16){
        float si = 0.f;
        for (int a = 0; a < 16; a++) si += pcs[a][tid];
        imps[tid] = si;
    }
    __syncthreads();
    for (int i = tid; i < HPG*DQK; i += 256){
        int h2 = i >> 7, d = i & 127;
        float o = 0.f;
        #pragma unroll
        for (int cc = 0; cc < 16; cc++) o += pcs[h2][cc] * vcs[cc][d];
        int hf = g*HPG + h2;
        o_acc[((size_t)s*NH + hf)*DQK + d] = gates[((size_t)s*NH + hf)*3 + 0] * o;
    }
    if (tid == 0){
        int cur = s >> 6;
        float sc[16];
        #pragma unroll
        for (int c2 = 0; c2 < 16; c2++){
            bool valid = (c2*BLKSZ) <= s;
            bool force = (c2 == 0) || (c2 == cur);
            sc[c2] = (valid && force) ? 1e9f : (valid ? imps[c2] : -1e9f);
        }
        int base = (s*NG + g)*TOPN;
        #pragma unroll
        for (int n = 0; n < TOPN; n++){
            float bv = -1e38f; int bi = 0;
            for (int c2 = 0; c2 < 16; c2++) if (sc[c2] > bv){ bv = sc[c2]; bi = c2; }
            idxb[base + n] = bi;
            sc[bi] = -1e38f;
        }
    }
}

// ---------------- fused MFMA selected + window attention ----------------
// Per (s,g) block, 4 waves.  S^T = mfma(K_rows, q_rows); P (gate/Z-folded, bf16)
// through LDS; O = mfma(P_rows, Vt_rows).  Writes final ob = bf16(o_acc + o_sel + o_win).
__global__ __launch_bounds__(256) void fused_attn(
    const float* __restrict__ q,            // [S][32][128] f32 (roped)
    const unsigned short* __restrict__ Kb,  // [S][2][128] bf16 (roped)
    const unsigned short* __restrict__ Vt,  // [2][128][S] bf16
    const float* __restrict__ gates,        // [S][32][3]
    const int* __restrict__ idxb,           // [S][2][4]
    const float* __restrict__ o_acc,        // [S][32][128] f32 (gated cmp)
    unsigned short* __restrict__ ob)        // [S][32][128] bf16
{
    const int s = blockIdx.x, g = blockIdx.y;
    const int tid = threadIdx.x;
    const int w = tid >> 6;
    const int lane = tid & 63;
    const int l15 = lane & 15;
    const int g4 = lane >> 4;
    __shared__ __align__(16) unsigned short P_lds[16][336];
    __shared__ float redm[4][16];
    __shared__ float reds[4][16];
    __shared__ int bidx[4];
    if (tid < 4) bidx[tid] = idxb[(s*NG + g)*TOPN + tid];

    // q b-frags: col h = l15, k = d
    bf16x8 qf[4];
    {
        const float* qrow = &q[((size_t)s*NH + g*HPG + l15)*DQK];
        #pragma unroll
        for (int ks = 0; ks < 4; ks++){
            int d0 = ks*32 + g4*8;
            f32x4 a = *(const f32x4*)(qrow + d0);
            f32x4 b = *(const f32x4*)(qrow + d0 + 4);
            bf16x8 r;
            #pragma unroll
            for (int i = 0; i < 4; i++){
                r[i]     = __builtin_bit_cast(__bf16, f2bf(a[i]));
                r[i + 4] = __builtin_bit_cast(__bf16, f2bf(b[i]));
            }
            qf[ks] = r;
        }
    }
    int wbase = (s >= 255) ? ((s - 255) & ~63) : 0;
    if (wbase > S_LEN - 320) wbase = S_LEN - 320;
    f32x4 oacc[2] = {};
    __syncthreads();

    #pragma unroll
    for (int br = 0; br < 2; br++){
        const int nkt = (br == 0) ? 4 : 5;       // key-tiles per wave
        const int wk0 = w * (nkt * 16);
        float sv[20];
        float mymax = -1e30f;
        #pragma unroll
        for (int kt = 0; kt < 5; kt++) if (kt < nkt){
            int key16 = wk0 + kt*16;
            int posA = (br == 0) ? (bidx[w]*64 + ((key16 + l15) & 63))
                                 : (wbase + key16 + l15);
            const unsigned short* krow = Kb + ((size_t)posA*NG + g)*DQK;
            f32x4 acc = {};
            #pragma unroll
            for (int ks2 = 0; ks2 < 4; ks2++){
                bf16x8 kf = *(const bf16x8*)(krow + ks2*32 + g4*8);
                acc = __builtin_amdgcn_mfma_f32_16x16x32_bf16(kf, qf[ks2], acc, 0, 0, 0);
            }
            #pragma unroll
            for (int j = 0; j < 4; j++){
                int key = key16 + g4*4 + j;           // row of S^T
                int pos = (br == 0) ? (bidx[w]*64 + (key & 63)) : (wbase + key);
                float v = acc[j] * SCALE;
                bool ok = (pos <= s) && (br == 0 || pos + WIN > s);
                sv[kt*4 + j] = ok ? v : -1e30f;
                mymax = fmaxf(mymax, sv[kt*4 + j]);
            }
        }
        mymax = fmaxf(mymax, __shfl_xor(mymax, 16));
        mymax = fmaxf(mymax, __shfl_xor(mymax, 32));
        if (lane < 16) redm[w][lane] = mymax;
        __syncthreads();
        float gm = fmaxf(fmaxf(redm[0][l15], redm[1][l15]),
                         fmaxf(redm[2][l15], redm[3][l15]));
        float mysum = 0.f;
        #pragma unroll
        for (int kt = 0; kt < 5; kt++) if (kt < nkt)
            #pragma unroll
            for (int j = 0; j < 4; j++){
                float e = (sv[kt*4 + j] > -1e29f) ? __expf(sv[kt*4 + j] - gm) : 0.f;
                sv[kt*4 + j] = e;
                mysum += e;
            }
        mysum += __shfl_xor(mysum, 16);
        mysum += __shfl_xor(mysum, 32);
        if (lane < 16) reds[w][lane] = mysum;
        __syncthreads();
        float Z = reds[0][l15] + reds[1][l15] + reds[2][l15] + reds[3][l15];
        float gate = gates[((size_t)s*NH + g*HPG + l15)*3 + 1 + br];
        float fac = gate / Z;
        #pragma unroll
        for (int kt = 0; kt < 5; kt++) if (kt < nkt)
            #pragma unroll
            for (int jp = 0; jp < 2; jp++){
                int key = wk0 + kt*16 + g4*4 + jp*2;
                unsigned int pk = (unsigned int)f2bf(sv[kt*4 + jp*2] * fac)
                                | ((unsigned int)f2bf(sv[kt*4 + jp*2 + 1] * fac) << 16);
                *(unsigned int*)&P_lds[l15][key] = pk;
            }
        __syncthreads();
        const int nks = (br == 0) ? 8 : 10;
        #pragma unroll
        for (int ks2 = 0; ks2 < 10; ks2++) if (ks2 < nks){
            bf16x8 pf = *(const bf16x8*)(&P_lds[l15][ks2*32 + g4*8]);
            int pos0 = (br == 0) ? (bidx[ks2 >> 1]*64 + (ks2 & 1)*32 + g4*8)
                                 : (wbase + ks2*32 + g4*8);
            #pragma unroll
            for (int dt = 0; dt < 2; dt++){
                int d = (2*w + dt)*16 + l15;
                bf16x8 vf = *(const bf16x8*)(Vt + ((size_t)g*DQK + d)*S_LEN + pos0);
                oacc[dt] = __builtin_amdgcn_mfma_f32_16x16x32_bf16(pf, vf, oacc[dt], 0, 0, 0);
            }
        }
        __syncthreads();
    }
    #pragma unroll
    for (int dt = 0; dt < 2; dt++){
        int d = (2*w + dt)*16 + l15;
        #pragma unroll
        for (int j = 0; j < 4; j++){
            int h = g4*4 + j;
            size_t oo = ((size_t)s*NH + g*HPG + h)*DQK + d;
            ob[oo] = f2bf(o_acc[oo] + oacc[dt][j]);
        }
    }
}

extern "C" void kernel_launch(void* const* d_in, const int* in_sizes, int n_in,
                              void* d_out, int out_size, void* d_ws, size_t ws_size,
                              hipStream_t stream)
{
    (void)in_sizes; (void)n_in; (void)out_size; (void)ws_size;
    const float* x    = (const float*)d_in[0];
    const float* cosb = (const float*)d_in[1];
    const float* sinb = (const float*)d_in[2];
    const float* Wq   = (const float*)d_in[3];
    const float* Wk   = (const float*)d_in[4];
    const float* Wv   = (const float*)d_in[5];
    const float* Wo   = (const float*)d_in[6];
    const float* Wc   = (const float*)d_in[7];
    float* out = (float*)d_out;

    char* ws = (char*)d_ws;
    size_t off = 0;
    auto alloc = [&](size_t bytes)->char*{
        char* p = ws + off;
        off += (bytes + 255) & ~(size_t)255;
        return p;
    };
    unsigned short* WqT_hi = (unsigned short*)alloc(4096ull*2048*2); // later: o_acc
    unsigned short* WqT_lo = (unsigned short*)alloc(4096ull*2048*2); // later: WoT
    unsigned short* xb_hi  = (unsigned short*)alloc(1024ull*2048*2); // later: ob (spans xb_hi+xb_lo)
    unsigned short* xb_lo  = (unsigned short*)alloc(1024ull*2048*2);
    unsigned short* WkT_hi = (unsigned short*)alloc(256ull*2048*2);  // later: Kbb
    unsigned short* WkT_lo = (unsigned short*)alloc(256ull*2048*2);  // later: Vt
    unsigned short* WvT    = (unsigned short*)alloc(256ull*2048*2);
    unsigned short* WcT    = (unsigned short*)alloc(96ull*2048*2);
    float* qbuf  = (float*)alloc(1024ull*32*128*4);
    float* kbuf  = (float*)alloc(1024ull*2*128*4);
    float* vbuf  = (float*)alloc(1024ull*2*128*4);
    float* gbuf  = (float*)alloc(1024ull*96*4);
    float* kcb   = (float*)alloc(16ull*2*128*4);
    float* vcb   = (float*)alloc(16ull*2*128*4);
    int*   idxb  = (int*)alloc(1024ull*2*4*4);
    float* o_acc = (float*)WqT_hi;            // alias (free after q GEMMs)
    unsigned short* WoT = WqT_lo;             // alias (free after q GEMMs)
    unsigned short* ob  = xb_hi;              // alias (free after k/v/gates GEMMs)
    unsigned short* Kbb = WkT_hi;             // alias (free after k GEMMs)
    unsigned short* Vt  = WkT_lo;             // alias (free after k GEMMs)

    // 1. split-convert x
    split_convert<<<dim3((1024*2048)/256), 256, 0, stream>>>(x, xb_hi, xb_lo, 1024*2048);
    // 2. transpose+convert weights
    transpose_split<<<dim3(4096/32, 2048/32), dim3(32,32), 0, stream>>>(Wq, WqT_hi, WqT_lo, 2048, 4096);
    transpose_split<<<dim3(256/32, 2048/32), dim3(32,32), 0, stream>>>(Wk, WkT_hi, WkT_lo, 2048, 256);
    transpose_split<<<dim3(256/32, 2048/32), dim3(32,32), 0, stream>>>(Wv, WvT, nullptr, 2048, 256);
    transpose_split<<<dim3(3, 2048/32), dim3(32,32), 0, stream>>>(Wc, WcT, nullptr, 2048, 96);
    // 3. q = x@Wq via 3-pass split-bf16 (fp32-equivalent accuracy for topk)
    gemm_bf16<0,false><<<dim3(64,16), 256, 0, stream>>>(xb_hi, WqT_hi, qbuf, 1024, 4096, 2048);
    gemm_bf16<0,true ><<<dim3(64,16), 256, 0, stream>>>(xb_hi, WqT_lo, qbuf, 1024, 4096, 2048);
    gemm_bf16<0,true ><<<dim3(64,16), 256, 0, stream>>>(xb_lo, WqT_hi, qbuf, 1024, 4096, 2048);
    // 4. k = x@Wk (split)
    gemm_bf16<0,false><<<dim3(4,16), 256, 0, stream>>>(xb_hi, WkT_hi, kbuf, 1024, 256, 2048);
    gemm_bf16<0,true ><<<dim3(4,16), 256, 0, stream>>>(xb_hi, WkT_lo, kbuf, 1024, 256, 2048);
    gemm_bf16<0,true ><<<dim3(4,16), 256, 0, stream>>>(xb_lo, WkT_hi, kbuf, 1024, 256, 2048);
    // 5. v, gates (plain bf16)
    gemm_bf16<0,false><<<dim3(4,16), 256, 0, stream>>>(xb_hi, WvT, vbuf, 1024, 256, 2048);
    gemm_bf16<1,false><<<dim3(2,16), 256, 0, stream>>>(xb_hi, WcT, gbuf, 1024, 96, 2048);
    // 6. RoPE in place
    rope_kernel<<<dim3((1024*32*64)/256), 256, 0, stream>>>(qbuf, cosb, sinb, 32, 1024*32*64);
    rope_kernel<<<dim3((1024*2*64)/256), 256, 0, stream>>>(kbuf, cosb, sinb, 2, 1024*2*64);
    // 7. block means (kc from RoPE'd k; vc from v)
    mean_blocks<<<dim3(16), 256, 0, stream>>>(kbuf, kcb);
    mean_blocks<<<dim3(16), 256, 0, stream>>>(vbuf, vcb);
    // 8. bf16 copies for MFMA attention (K rows; V transposed)
    kb_convert<<<dim3((1024*2*128/4 + 255)/256), 256, 0, stream>>>(kbuf, Kbb, 1024*2*128/4);
    vt_transpose<<<dim3(1024/32, 128/32, 2), dim3(32,32), 0, stream>>>(vbuf, Vt);
    // 9. Wo transpose (WqT_lo region now free)
    transpose_split<<<dim3(2048/32, 4096/32), dim3(32,32), 0, stream>>>(Wo, WoT, nullptr, 4096, 2048);
    // 10. compressed attention (fp32) -> gated o_acc + topk indices
    cmp_attn<<<dim3(1024,2), 256, 0, stream>>>(qbuf, kcb, vcb, gbuf, o_acc, idxb);
    // 11. fused MFMA selected+window attention -> final o (bf16)
    fused_attn<<<dim3(1024,2), 256, 0, stream>>>(qbuf, Kbb, Vt, gbuf, idxb, o_acc, ob);
    // 12. out = o @ Wo
    gemm_bf16<0,false><<<dim3(32,16), 256, 0, stream>>>(ob, WoT, out, 1024, 2048, 4096);
}

// Round 3
// 512.213 us; speedup vs baseline: 2.1300x; 1.3385x over previous
//
#include <hip/hip_runtime.h>

#define S_LEN 1024
#define DMODEL 2048
#define NH 32
#define NG 2
#define HPG 16
#define DQK 128
#define NBLK 16
#define BLKSZ 64
#define TOPN 4
#define WIN 256
#define SCALE 0.08838834764831845f

typedef float f32x4 __attribute__((ext_vector_type(4)));
typedef __bf16 bf16x8 __attribute__((ext_vector_type(8)));

__device__ __forceinline__ unsigned short f2bf(float f){
    unsigned int u = __builtin_bit_cast(unsigned int, f);
    u += 0x7fffu + ((u >> 16) & 1u);
    return (unsigned short)(u >> 16);
}
__device__ __forceinline__ float bf2f(unsigned short h){
    unsigned int u = ((unsigned int)h) << 16;
    return __builtin_bit_cast(float, u);
}

using as1_u32 = __attribute__((address_space(1))) const unsigned int;
using as3_u32 = __attribute__((address_space(3))) unsigned int;
__device__ __forceinline__ void g2l16(const void* g, void* l){
    __builtin_amdgcn_global_load_lds((as1_u32*)g, (as3_u32*)l, 16, 0, 0);
}

// ---------------- split convert: x -> hi bf16, lo bf16 ----------------
__global__ __launch_bounds__(256) void split_convert(
    const float* __restrict__ in, unsigned short* __restrict__ hi,
    unsigned short* __restrict__ lo, int n)
{
    int i = blockIdx.x * 256 + threadIdx.x;
    if (i < n){
        float v = in[i];
        unsigned short h = f2bf(v);
        hi[i] = h;
        lo[i] = f2bf(v - bf2f(h));
    }
}

// ---------------- transpose W[K][N] -> WT[N][K] (bf16 hi, optional lo) ----------------
__global__ __launch_bounds__(1024) void transpose_split(
    const float* __restrict__ W, unsigned short* __restrict__ WT_hi,
    unsigned short* __restrict__ WT_lo, int K, int N)
{
    __shared__ float t[32][33];
    int tx = threadIdx.x, ty = threadIdx.y;
    int k0 = blockIdx.y * 32, n0 = blockIdx.x * 32;
    int nn = n0 + tx;
    float val = 0.f;
    if (nn < N) val = W[(size_t)(k0 + ty) * N + nn];
    t[ty][tx] = val;
    __syncthreads();
    int n2 = n0 + ty;
    if (n2 < N){
        float v2 = t[tx][ty];
        unsigned short h = f2bf(v2);
        WT_hi[(size_t)n2 * K + k0 + tx] = h;
        if (WT_lo){
            WT_lo[(size_t)n2 * K + k0 + tx] = f2bf(v2 - bf2f(h));
        }
    }
}

// ---- fused (optionally split-precision) MFMA GEMM ----
// C[M][N] = A[M][K] * BT[N][K]^T ;  NTERM==3: A=Ah+Al, B=Bh+Bl, acc gets
// Ah*Bh + Ah*Bl + Al*Bh (fp32-equivalent).  MODE: 0 plain, 1 sigmoid.
// BM=128, BN=64, BK=64, 256 threads (4 waves, each 64x32 = 4x2 frags).
template<int NTERM, int MODE>
__global__ __launch_bounds__(256) void gemm_fused(
    const unsigned short* __restrict__ Ah, const unsigned short* __restrict__ Al,
    const unsigned short* __restrict__ Bh, const unsigned short* __restrict__ Bl,
    float* __restrict__ Co, int M, int N, int K)
{
    __shared__ __align__(16) unsigned short smem[NTERM == 3 ? 24576 : 12288];
    unsigned short* As_h = smem;            // [128][64]
    unsigned short* Bs_h = smem + 8192;     // [64][64]
    unsigned short* As_l = smem + 12288;    // NTERM==3 only
    unsigned short* Bs_l = smem + 20480;

    // XCD-aware bijective block swizzle (all launch grids are %8==0)
    int gx = gridDim.x;
    int nwg = gx * gridDim.y;
    int bid = blockIdx.y * gx + blockIdx.x;
    int chunk = nwg >> 3;
    bid = (bid & 7) * chunk + (bid >> 3);
    const int n0 = (bid % gx) * 64;
    const int m0 = (bid / gx) * 128;

    const int tid = threadIdx.x;
    const int lane = tid & 63;
    const int l15 = lane & 15;
    const int g4 = lane >> 4;
    const int w = tid >> 6;
    const int wr = w >> 1, wc = w & 1;
    const int ar = tid >> 3;            // staging row 0..31
    const int ac = (tid & 7) * 8;       // staging col (8 bf16 = 16B)

    f32x4 acc[4][2] = {};

    for (int k0 = 0; k0 < K; k0 += 64){
        #pragma unroll
        for (int p = 0; p < 4; p++){
            int r = p*32 + ar;
            size_t go = (size_t)(m0 + r) * K + k0 + ac;
            int lo_ = p*2048 + tid*8;
            g2l16(Ah + go, As_h + lo_);
            if constexpr (NTERM == 3) g2l16(Al + go, As_l + lo_);
        }
        #pragma unroll
        for (int p = 0; p < 2; p++){
            int r = p*32 + ar;
            int nr = n0 + r; if (nr > N - 1) nr = N - 1;   // clamp (cols >= N masked at write)
            size_t go = (size_t)nr * K + k0 + ac;
            int lo_ = p*2048 + tid*8;
            g2l16(Bh + go, Bs_h + lo_);
            if constexpr (NTERM == 3) g2l16(Bl + go, Bs_l + lo_);
        }
        __syncthreads();
        #pragma unroll
        for (int ks = 0; ks < 2; ks++){
            const int kc_ = ks*32 + g4*8;
            bf16x8 ah[4], bh[2], al[4], bl[2];
            #pragma unroll
            for (int mi = 0; mi < 4; mi++){
                int row = wr*64 + mi*16 + l15;
                ah[mi] = *(const bf16x8*)&As_h[row*64 + kc_];
                if constexpr (NTERM == 3) al[mi] = *(const bf16x8*)&As_l[row*64 + kc_];
            }
            #pragma unroll
            for (int ni = 0; ni < 2; ni++){
                int row = wc*32 + ni*16 + l15;
                bh[ni] = *(const bf16x8*)&Bs_h[row*64 + kc_];
                if constexpr (NTERM == 3) bl[ni] = *(const bf16x8*)&Bs_l[row*64 + kc_];
            }
            #pragma unroll
            for (int mi = 0; mi < 4; mi++)
                #pragma unroll
                for (int ni = 0; ni < 2; ni++){
                    acc[mi][ni] = __builtin_amdgcn_mfma_f32_16x16x32_bf16(
                        ah[mi], bh[ni], acc[mi][ni], 0, 0, 0);
                    if constexpr (NTERM == 3){
                        acc[mi][ni] = __builtin_amdgcn_mfma_f32_16x16x32_bf16(
                            ah[mi], bl[ni], acc[mi][ni], 0, 0, 0);
                        acc[mi][ni] = __builtin_amdgcn_mfma_f32_16x16x32_bf16(
                            al[mi], bh[ni], acc[mi][ni], 0, 0, 0);
                    }
                }
        }
        __syncthreads();
    }
    #pragma unroll
    for (int mi = 0; mi < 4; mi++)
        #pragma unroll
        for (int ni = 0; ni < 2; ni++){
            int col = n0 + wc*32 + ni*16 + l15;
            if (col < N){
                int rbase = m0 + wr*64 + mi*16 + g4*4;
                #pragma unroll
                for (int j = 0; j < 4; j++){
                    float v = acc[mi][ni][j];
                    if (MODE == 1) v = 1.f / (1.f + __expf(-v));
                    Co[(size_t)(rbase + j) * N + col] = v;
                }
            }
        }
}

// ---------------- RoPE (in place), t: [S][nh][128] ----------------
__global__ __launch_bounds__(256) void rope_kernel(
    float* __restrict__ t, const float* __restrict__ cosb,
    const float* __restrict__ sinb, int nh, int total)
{
    int i = blockIdx.x * 256 + threadIdx.x;
    if (i >= total) return;
    int d = i & 63;
    int r = i >> 6;
    int s = r / nh;
    size_t base = (size_t)r * 128;
    float lo_v = t[base + d], hi_v = t[base + 64 + d];
    float cl = cosb[s*128 + d],      sl = sinb[s*128 + d];
    float ch = cosb[s*128 + 64 + d], sh = sinb[s*128 + 64 + d];
    t[base + d]      = lo_v * cl - hi_v * sl;
    t[base + 64 + d] = hi_v * ch + lo_v * sh;
}

// ---------------- block means: src [S][G][128] -> dst [C][G][128] ----------------
__global__ __launch_bounds__(256) void mean_blocks(
    const float* __restrict__ src, float* __restrict__ dst)
{
    int i = blockIdx.x * 256 + threadIdx.x;
    if (i >= NBLK * NG * DQK) return;
    int d = i & 127;
    int g = (i >> 7) & 1;
    int c = i >> 8;
    float s_ = 0.f;
    for (int j = 0; j < BLKSZ; j++)
        s_ += src[((size_t)(c*BLKSZ + j) * NG + g) * DQK + d];
    dst[i] = s_ * (1.f / 64.f);
}

// ---------------- kbuf f32 -> bf16 copy ----------------
__global__ __launch_bounds__(256) void kb_convert(
    const float* __restrict__ in, unsigned short* __restrict__ out, int n4)
{
    int i = blockIdx.x * 256 + threadIdx.x;
    if (i < n4){
        f32x4 v = ((const f32x4*)in)[i];
        ushort4 o;
        o.x = f2bf(v[0]); o.y = f2bf(v[1]); o.z = f2bf(v[2]); o.w = f2bf(v[3]);
        ((ushort4*)out)[i] = o;
    }
}

// ---------------- vbuf [S][G][128] f32 -> Vt [G][128][S] bf16 ----------------
__global__ __launch_bounds__(1024) void vt_transpose(
    const float* __restrict__ v, unsigned short* __restrict__ Vt)
{
    __shared__ float t[32][33];
    int g = blockIdx.z;
    int s0 = blockIdx.x * 32, d0 = blockIdx.y * 32;
    int tx = threadIdx.x, ty = threadIdx.y;
    t[ty][tx] = v[((size_t)(s0 + ty)*NG + g)*DQK + d0 + tx];
    __syncthreads();
    Vt[((size_t)g*DQK + d0 + ty)*S_LEN + s0 + tx] = f2bf(t[tx][ty]);
}

// ---------------- compressed attention + importance + topk (fp32, padded LDS) ----------------
__global__ __launch_bounds__(256) void cmp_attn(
    const float* __restrict__ q, const float* __restrict__ kc,
    const float* __restrict__ vc, const float* __restrict__ gates,
    float* __restrict__ o_acc, int* __restrict__ idxb)
{
    int s = blockIdx.x, g = blockIdx.y;
    __shared__ float qs[16][132];
    __shared__ float kcs[16][132];
    __shared__ float vcs[16][132];
    __shared__ float pcs[16][16];
    __shared__ float imps[16];
    int tid = threadIdx.x;
    for (int i = tid; i < 16*128; i += 256){
        int a = i >> 7, d = i & 127;
        qs[a][d]  = q[((size_t)s*NH + g*HPG + a)*DQK + d];
        kcs[a][d] = kc[((size_t)a*NG + g)*DQK + d];
        vcs[a][d] = vc[((size_t)a*NG + g)*DQK + d];
    }
    __syncthreads();
    int hh = tid >> 4, c = tid & 15;
    float acc = 0.f;
    for (int d4 = 0; d4 < 128; d4 += 4){
        f32x4 qv = *(const f32x4*)&qs[hh][d4];
        f32x4 kv = *(const f32x4*)&kcs[c][d4];
        acc += qv[0]*kv[0] + qv[1]*kv[1] + qv[2]*kv[2] + qv[3]*kv[3];
    }
    acc *= SCALE;
    bool vis = ((c + 1)*BLKSZ - 1) <= s;
    float l = vis ? acc : -1e30f;
    float m = l;
    #pragma unroll
    for (int off = 1; off < 16; off <<= 1) m = fmaxf(m, __shfl_xor(m, off));
    float p = vis ? __expf(l - m) : 0.f;
    float Z = p;
    #pragma unroll
    for (int off = 1; off < 16; off <<= 1) Z += __shfl_xor(Z, off);
    p = (Z > 0.f) ? (p / Z) : 0.f;
    pcs[hh][c] = p;
    __syncthreads();
    if (tid < 16){
        float si = 0.f;
        for (int a = 0; a < 16; a++) si += pcs[a][tid];
        imps[tid] = si;
    }
    __syncthreads();
    for (int i = tid; i < HPG*DQK; i += 256){
        int h2 = i >> 7, d = i & 127;
        float o = 0.f;
        #pragma unroll
        for (int cc = 0; cc < 16; cc++) o += pcs[h2][cc] * vcs[cc][d];
        int hf = g*HPG + h2;
        o_acc[((size_t)s*NH + hf)*DQK + d] = gates[((size_t)s*NH + hf)*3 + 0] * o;
    }
    if (tid == 0){
        int cur = s >> 6;
        float sc[16];
        #pragma unroll
        for (int c2 = 0; c2 < 16; c2++){
            bool valid = (c2*BLKSZ) <= s;
            bool force = (c2 == 0) || (c2 == cur);
            sc[c2] = (valid && force) ? 1e9f : (valid ? imps[c2] : -1e9f);
        }
        int base = (s*NG + g)*TOPN;
        #pragma unroll
        for (int n = 0; n < TOPN; n++){
            float bv = -1e38f; int bi = 0;
            for (int c2 = 0; c2 < 16; c2++) if (sc[c2] > bv){ bv = sc[c2]; bi = c2; }
            idxb[base + n] = bi;
            sc[bi] = -1e38f;
        }
    }
}

// ---------------- fused MFMA selected + window attention ----------------
__global__ __launch_bounds__(256) void fused_attn(
    const float* __restrict__ q,            // [S][32][128] f32 (roped)
    const unsigned short* __restrict__ Kb,  // [S][2][128] bf16 (roped)
    const unsigned short* __restrict__ Vt,  // [2][128][S] bf16
    const float* __restrict__ gates,        // [S][32][3]
    const int* __restrict__ idxb,           // [S][2][4]
    const float* __restrict__ o_acc,        // [S][32][128] f32 (gated cmp)
    unsigned short* __restrict__ ob)        // [S][32][128] bf16
{
    const int s = blockIdx.x, g = blockIdx.y;
    const int tid = threadIdx.x;
    const int w = tid >> 6;
    const int lane = tid & 63;
    const int l15 = lane & 15;
    const int g4 = lane >> 4;
    __shared__ __align__(16) unsigned short P_lds[16][336];
    __shared__ float redm[4][16];
    __shared__ float reds[4][16];
    __shared__ int bidx[4];
    if (tid < 4) bidx[tid] = idxb[(s*NG + g)*TOPN + tid];

    bf16x8 qf[4];
    {
        const float* qrow = &q[((size_t)s*NH + g*HPG + l15)*DQK];
        #pragma unroll
        for (int ks = 0; ks < 4; ks++){
            int d0 = ks*32 + g4*8;
            f32x4 a = *(const f32x4*)(qrow + d0);
            f32x4 b = *(const f32x4*)(qrow + d0 + 4);
            bf16x8 r;
            #pragma unroll
            for (int i = 0; i < 4; i++){
                r[i]     = __builtin_bit_cast(__bf16, f2bf(a[i]));
                r[i + 4] = __builtin_bit_cast(__bf16, f2bf(b[i]));
            }
            qf[ks] = r;
        }
    }
    int wbase = (s >= 255) ? ((s - 255) & ~63) : 0;
    if (wbase > S_LEN - 320) wbase = S_LEN - 320;
    f32x4 oacc[2] = {};
    __syncthreads();

    #pragma unroll
    for (int br = 0; br < 2; br++){
        const int nkt = (br == 0) ? 4 : 5;
        const int wk0 = w * (nkt * 16);
        float sv[20];
        float mymax = -1e30f;
        #pragma unroll
        for (int kt = 0; kt < 5; kt++) if (kt < nkt){
            int key16 = wk0 + kt*16;
            int posA = (br == 0) ? (bidx[w]*64 + ((key16 + l15) & 63))
                                 : (wbase + key16 + l15);
            const unsigned short* krow = Kb + ((size_t)posA*NG + g)*DQK;
            f32x4 acc = {};
            #pragma unroll
            for (int ks2 = 0; ks2 < 4; ks2++){
                bf16x8 kf = *(const bf16x8*)(krow + ks2*32 + g4*8);
                acc = __builtin_amdgcn_mfma_f32_16x16x32_bf16(kf, qf[ks2], acc, 0, 0, 0);
            }
            #pragma unroll
            for (int j = 0; j < 4; j++){
                int key = key16 + g4*4 + j;
                int pos = (br == 0) ? (bidx[w]*64 + (key & 63)) : (wbase + key);
                float v = acc[j] * SCALE;
                bool ok = (pos <= s) && (br == 0 || pos + WIN > s);
                sv[kt*4 + j] = ok ? v : -1e30f;
                mymax = fmaxf(mymax, sv[kt*4 + j]);
            }
        }
        mymax = fmaxf(mymax, __shfl_xor(mymax, 16));
        mymax = fmaxf(mymax, __shfl_xor(mymax, 32));
        if (lane < 16) redm[w][lane] = mymax;
        __syncthreads();
        float gm = fmaxf(fmaxf(redm[0][l15], redm[1][l15]),
                         fmaxf(redm[2][l15], redm[3][l15]));
        float mysum = 0.f;
        #pragma unroll
        for (int kt = 0; kt < 5; kt++) if (kt < nkt)
            #pragma unroll
            for (int j = 0; j < 4; j++){
                float e = (sv[kt*4 + j] > -1e29f) ? __expf(sv[kt*4 + j] - gm) : 0.f;
                sv[kt*4 + j] = e;
                mysum += e;
            }
        mysum += __shfl_xor(mysum, 16);
        mysum += __shfl_xor(mysum, 32);
        if (lane < 16) reds[w][lane] = mysum;
        __syncthreads();
        float Z = reds[0][l15] + reds[1][l15] + reds[2][l15] + reds[3][l15];
        float gate = gates[((size_t)s*NH + g*HPG + l15)*3 + 1 + br];
        float fac = gate / Z;
        #pragma unroll
        for (int kt = 0; kt < 5; kt++) if (kt < nkt)
            #pragma unroll
            for (int jp = 0; jp < 2; jp++){
                int key = wk0 + kt*16 + g4*4 + jp*2;
                unsigned int pk = (unsigned int)f2bf(sv[kt*4 + jp*2] * fac)
                                | ((unsigned int)f2bf(sv[kt*4 + jp*2 + 1] * fac) << 16);
                *(unsigned int*)&P_lds[l15][key] = pk;
            }
        __syncthreads();
        const int nks = (br == 0) ? 8 : 10;
        #pragma unroll
        for (int ks2 = 0; ks2 < 10; ks2++) if (ks2 < nks){
            bf16x8 pf = *(const bf16x8*)(&P_lds[l15][ks2*32 + g4*8]);
            int pos0 = (br == 0) ? (bidx[ks2 >> 1]*64 + (ks2 & 1)*32 + g4*8)
                                 : (wbase + ks2*32 + g4*8);
            #pragma unroll
            for (int dt = 0; dt < 2; dt++){
                int d = (2*w + dt)*16 + l15;
                bf16x8 vf = *(const bf16x8*)(Vt + ((size_t)g*DQK + d)*S_LEN + pos0);
                oacc[dt] = __builtin_amdgcn_mfma_f32_16x16x32_bf16(pf, vf, oacc[dt], 0, 0, 0);
            }
        }
        __syncthreads();
    }
    #pragma unroll
    for (int dt = 0; dt < 2; dt++){
        int d = (2*w + dt)*16 + l15;
        #pragma unroll
        for (int j = 0; j < 4; j++){
            int h = g4*4 + j;
            size_t oo = ((size_t)s*NH + g*HPG + h)*DQK + d;
            ob[oo] = f2bf(o_acc[oo] + oacc[dt][j]);
        }
    }
}

extern "C" void kernel_launch(void* const* d_in, const int* in_sizes, int n_in,
                              void* d_out, int out_size, void* d_ws, size_t ws_size,
                              hipStream_t stream)
{
    (void)in_sizes; (void)n_in; (void)out_size; (void)ws_size;
    const float* x    = (const float*)d_in[0];
    const float* cosb = (const float*)d_in[1];
    const float* sinb = (const float*)d_in[2];
    const float* Wq   = (const float*)d_in[3];
    const float* Wk   = (const float*)d_in[4];
    const float* Wv   = (const float*)d_in[5];
    const float* Wo   = (const float*)d_in[6];
    const float* Wc   = (const float*)d_in[7];
    float* out = (float*)d_out;

    char* ws = (char*)d_ws;
    size_t off = 0;
    auto alloc = [&](size_t bytes)->char*{
        char* p = ws + off;
        off += (bytes + 255) & ~(size_t)255;
        return p;
    };
    unsigned short* WqT_hi = (unsigned short*)alloc(4096ull*2048*2); // later: o_acc
    unsigned short* WqT_lo = (unsigned short*)alloc(4096ull*2048*2); // later: WoT
    unsigned short* xb_hi  = (unsigned short*)alloc(1024ull*2048*2); // later: ob
    unsigned short* xb_lo  = (unsigned short*)alloc(1024ull*2048*2);
    unsigned short* WkT_hi = (unsigned short*)alloc(256ull*2048*2);  // later: Kbb
    unsigned short* WkT_lo = (unsigned short*)alloc(256ull*2048*2);  // later: Vt
    unsigned short* WvT    = (unsigned short*)alloc(256ull*2048*2);
    unsigned short* WcT    = (unsigned short*)alloc(96ull*2048*2);
    float* qbuf  = (float*)alloc(1024ull*32*128*4);
    float* kbuf  = (float*)alloc(1024ull*2*128*4);
    float* vbuf  = (float*)alloc(1024ull*2*128*4);
    float* gbuf  = (float*)alloc(1024ull*96*4);
    float* kcb   = (float*)alloc(16ull*2*128*4);
    float* vcb   = (float*)alloc(16ull*2*128*4);
    int*   idxb  = (int*)alloc(1024ull*2*4*4);
    float* o_acc = (float*)WqT_hi;            // alias (free after q GEMM)
    unsigned short* WoT = WqT_lo;             // alias (free after q GEMM)
    unsigned short* ob  = xb_hi;              // alias (free after k/v/gates GEMMs)
    unsigned short* Kbb = WkT_hi;             // alias (free after k GEMM)
    unsigned short* Vt  = WkT_lo;             // alias (free after k GEMM)

    // 1. split-convert x
    split_convert<<<dim3((1024*2048)/256), 256, 0, stream>>>(x, xb_hi, xb_lo, 1024*2048);
    // 2. transpose+convert weights
    transpose_split<<<dim3(4096/32, 2048/32), dim3(32,32), 0, stream>>>(Wq, WqT_hi, WqT_lo, 2048, 4096);
    transpose_split<<<dim3(256/32, 2048/32), dim3(32,32), 0, stream>>>(Wk, WkT_hi, WkT_lo, 2048, 256);
    transpose_split<<<dim3(256/32, 2048/32), dim3(32,32), 0, stream>>>(Wv, WvT, nullptr, 2048, 256);
    transpose_split<<<dim3(3, 2048/32), dim3(32,32), 0, stream>>>(Wc, WcT, nullptr, 2048, 96);
    // 3. q = x@Wq — single fused split pass (3 MFMA terms / fragment)
    gemm_fused<3,0><<<dim3(64,8), 256, 0, stream>>>(xb_hi, xb_lo, WqT_hi, WqT_lo, qbuf, 1024, 4096, 2048);
    // 4. k = x@Wk — fused split
    gemm_fused<3,0><<<dim3(4,8), 256, 0, stream>>>(xb_hi, xb_lo, WkT_hi, WkT_lo, kbuf, 1024, 256, 2048);
    // 5. v, gates (plain bf16)
    gemm_fused<1,0><<<dim3(4,8), 256, 0, stream>>>(xb_hi, nullptr, WvT, nullptr, vbuf, 1024, 256, 2048);
    gemm_fused<1,1><<<dim3(2,8), 256, 0, stream>>>(xb_hi, nullptr, WcT, nullptr, gbuf, 1024, 96, 2048);
    // 6. RoPE in place
    rope_kernel<<<dim3((1024*32*64)/256), 256, 0, stream>>>(qbuf, cosb, sinb, 32, 1024*32*64);
    rope_kernel<<<dim3((1024*2*64)/256), 256, 0, stream>>>(kbuf, cosb, sinb, 2, 1024*2*64);
    // 7. block means
    mean_blocks<<<dim3(16), 256, 0, stream>>>(kbuf, kcb);
    mean_blocks<<<dim3(16), 256, 0, stream>>>(vbuf, vcb);
    // 8. bf16 copies for MFMA attention
    kb_convert<<<dim3((1024*2*128/4 + 255)/256), 256, 0, stream>>>(kbuf, Kbb, 1024*2*128/4);
    vt_transpose<<<dim3(1024/32, 128/32, 2), dim3(32,32), 0, stream>>>(vbuf, Vt);
    // 9. Wo transpose
    transpose_split<<<dim3(2048/32, 4096/32), dim3(32,32), 0, stream>>>(Wo, WoT, nullptr, 4096, 2048);
    // 10. compressed attention -> gated o_acc + topk indices
    cmp_attn<<<dim3(1024,2), 256, 0, stream>>>(qbuf, kcb, vcb, gbuf, o_acc, idxb);
    // 11. fused MFMA selected+window attention -> final o (bf16)
    fused_attn<<<dim3(1024,2), 256, 0, stream>>>(qbuf, Kbb, Vt, gbuf, idxb, o_acc, ob);
    // 12. out = o @ Wo
    gemm_fused<1,0><<<dim3(32,8), 256, 0, stream>>>(ob, nullptr, WoT, nullptr, out, 1024, 2048, 4096);
}

// Round 4
// 386.998 us; speedup vs baseline: 2.8192x; 1.3236x over previous
//
#include <hip/hip_runtime.h>

#define S_LEN 1024
#define DMODEL 2048
#define NH 32
#define NG 2
#define HPG 16
#define DQK 128
#define NBLK 16
#define BLKSZ 64
#define TOPN 4
#define WIN 256
#define SCALE 0.08838834764831845f

typedef float f32x4 __attribute__((ext_vector_type(4)));
typedef __bf16 bf16x8 __attribute__((ext_vector_type(8)));

__device__ __forceinline__ unsigned short f2bf(float f){
    unsigned int u = __builtin_bit_cast(unsigned int, f);
    u += 0x7fffu + ((u >> 16) & 1u);
    return (unsigned short)(u >> 16);
}
__device__ __forceinline__ float bf2f(unsigned short h){
    unsigned int u = ((unsigned int)h) << 16;
    return __builtin_bit_cast(float, u);
}

using as1_u32 = __attribute__((address_space(1))) const unsigned int;
using as3_u32 = __attribute__((address_space(3))) unsigned int;
__device__ __forceinline__ void g2l16(const void* g, void* l){
    __builtin_amdgcn_global_load_lds((as1_u32*)g, (as3_u32*)l, 16, 0, 0);
}

// ---------------- split convert: x -> hi bf16, lo bf16 ----------------
__global__ __launch_bounds__(256) void split_convert(
    const float* __restrict__ in, unsigned short* __restrict__ hi,
    unsigned short* __restrict__ lo, int n)
{
    int i = blockIdx.x * 256 + threadIdx.x;
    if (i < n){
        float v = in[i];
        unsigned short h = f2bf(v);
        hi[i] = h;
        lo[i] = f2bf(v - bf2f(h));
    }
}

// ---------------- transpose W[K][N] -> WT[N][K] (bf16 hi, optional lo) ----------------
__global__ __launch_bounds__(1024) void transpose_split(
    const float* __restrict__ W, unsigned short* __restrict__ WT_hi,
    unsigned short* __restrict__ WT_lo, int K, int N)
{
    __shared__ float t[32][33];
    int tx = threadIdx.x, ty = threadIdx.y;
    int k0 = blockIdx.y * 32, n0 = blockIdx.x * 32;
    int nn = n0 + tx;
    float val = 0.f;
    if (nn < N) val = W[(size_t)(k0 + ty) * N + nn];
    t[ty][tx] = val;
    __syncthreads();
    int n2 = n0 + ty;
    if (n2 < N){
        float v2 = t[tx][ty];
        unsigned short h = f2bf(v2);
        WT_hi[(size_t)n2 * K + k0 + tx] = h;
        if (WT_lo){
            WT_lo[(size_t)n2 * K + k0 + tx] = f2bf(v2 - bf2f(h));
        }
    }
}

// ---- fused (optionally split-precision) MFMA GEMM, optional split-K via gridDim.z ----
// Partial z writes to Co + z*M*N.  NTERM==3: acc += Ah*Bh + Ah*Bl + Al*Bh.
template<int NTERM, int MODE>
__global__ __launch_bounds__(256) void gemm_fused(
    const unsigned short* __restrict__ Ah, const unsigned short* __restrict__ Al,
    const unsigned short* __restrict__ Bh, const unsigned short* __restrict__ Bl,
    float* __restrict__ Co, int M, int N, int K)
{
    __shared__ __align__(16) unsigned short smem[NTERM == 3 ? 24576 : 12288];
    unsigned short* As_h = smem;            // [128][64]
    unsigned short* Bs_h = smem + 8192;     // [64][64]
    unsigned short* As_l = smem + 12288;    // NTERM==3 only
    unsigned short* Bs_l = smem + 20480;

    // XCD-aware bijective block swizzle (x*y grids are %8==0)
    int gx = gridDim.x;
    int nwg = gx * gridDim.y;
    int bid = blockIdx.y * gx + blockIdx.x;
    int chunk = nwg >> 3;
    bid = (bid & 7) * chunk + (bid >> 3);
    const int n0 = (bid % gx) * 64;
    const int m0 = (bid / gx) * 128;

    const int kz = blockIdx.z;
    const int Kloc = K / gridDim.z;
    const int kbeg = kz * Kloc;
    Co += (size_t)kz * M * N;

    const int tid = threadIdx.x;
    const int lane = tid & 63;
    const int l15 = lane & 15;
    const int g4 = lane >> 4;
    const int w = tid >> 6;
    const int wr = w >> 1, wc = w & 1;
    const int ar = tid >> 3;            // staging row 0..31
    const int ac = (tid & 7) * 8;       // staging col (8 bf16 = 16B)

    f32x4 acc[4][2] = {};

    for (int k0 = kbeg; k0 < kbeg + Kloc; k0 += 64){
        #pragma unroll
        for (int p = 0; p < 4; p++){
            int r = p*32 + ar;
            size_t go = (size_t)(m0 + r) * K + k0 + ac;
            int lo_ = p*2048 + tid*8;
            g2l16(Ah + go, As_h + lo_);
            if constexpr (NTERM == 3) g2l16(Al + go, As_l + lo_);
        }
        #pragma unroll
        for (int p = 0; p < 2; p++){
            int r = p*32 + ar;
            int nr = n0 + r; if (nr > N - 1) nr = N - 1;
            size_t go = (size_t)nr * K + k0 + ac;
            int lo_ = p*2048 + tid*8;
            g2l16(Bh + go, Bs_h + lo_);
            if constexpr (NTERM == 3) g2l16(Bl + go, Bs_l + lo_);
        }
        __syncthreads();
        #pragma unroll
        for (int ks = 0; ks < 2; ks++){
            const int kc_ = ks*32 + g4*8;
            bf16x8 ah[4], bh[2], al[4], bl[2];
            #pragma unroll
            for (int mi = 0; mi < 4; mi++){
                int row = wr*64 + mi*16 + l15;
                ah[mi] = *(const bf16x8*)&As_h[row*64 + kc_];
                if constexpr (NTERM == 3) al[mi] = *(const bf16x8*)&As_l[row*64 + kc_];
            }
            #pragma unroll
            for (int ni = 0; ni < 2; ni++){
                int row = wc*32 + ni*16 + l15;
                bh[ni] = *(const bf16x8*)&Bs_h[row*64 + kc_];
                if constexpr (NTERM == 3) bl[ni] = *(const bf16x8*)&Bs_l[row*64 + kc_];
            }
            #pragma unroll
            for (int mi = 0; mi < 4; mi++)
                #pragma unroll
                for (int ni = 0; ni < 2; ni++){
                    acc[mi][ni] = __builtin_amdgcn_mfma_f32_16x16x32_bf16(
                        ah[mi], bh[ni], acc[mi][ni], 0, 0, 0);
                    if constexpr (NTERM == 3){
                        acc[mi][ni] = __builtin_amdgcn_mfma_f32_16x16x32_bf16(
                            ah[mi], bl[ni], acc[mi][ni], 0, 0, 0);
                        acc[mi][ni] = __builtin_amdgcn_mfma_f32_16x16x32_bf16(
                            al[mi], bh[ni], acc[mi][ni], 0, 0, 0);
                    }
                }
        }
        __syncthreads();
    }
    #pragma unroll
    for (int mi = 0; mi < 4; mi++)
        #pragma unroll
        for (int ni = 0; ni < 2; ni++){
            int col = n0 + wc*32 + ni*16 + l15;
            if (col < N){
                int rbase = m0 + wr*64 + mi*16 + g4*4;
                #pragma unroll
                for (int j = 0; j < 4; j++){
                    float v = acc[mi][ni][j];
                    if (MODE == 1) v = 1.f / (1.f + __expf(-v));
                    Co[(size_t)(rbase + j) * N + col] = v;
                }
            }
        }
}

// ---------------- deterministic split-K reduce + routing (k | v | sigmoid gates) ----
__global__ __launch_bounds__(256) void reduce_kvg(
    const float* __restrict__ part, float* __restrict__ kbuf,
    float* __restrict__ vbuf, float* __restrict__ gbuf)
{
    int i = blockIdx.x * 256 + threadIdx.x;
    if (i >= 1024*608) return;
    int s = i / 608, c = i % 608;
    size_t o = (size_t)s * 640 + c;
    const size_t stride = 1024ull * 640;
    float sum = part[o] + part[o + stride] + part[o + 2*stride] + part[o + 3*stride];
    if (c < 256) kbuf[s*256 + c] = sum;
    else if (c < 512) vbuf[s*256 + (c - 256)] = sum;
    else gbuf[s*96 + (c - 512)] = 1.f / (1.f + __expf(-sum));
}

// ---------------- RoPE (in place), t: [S][nh][128] ----------------
__global__ __launch_bounds__(256) void rope_kernel(
    float* __restrict__ t, const float* __restrict__ cosb,
    const float* __restrict__ sinb, int nh, int total)
{
    int i = blockIdx.x * 256 + threadIdx.x;
    if (i >= total) return;
    int d = i & 63;
    int r = i >> 6;
    int s = r / nh;
    size_t base = (size_t)r * 128;
    float lo_v = t[base + d], hi_v = t[base + 64 + d];
    float cl = cosb[s*128 + d],      sl = sinb[s*128 + d];
    float ch = cosb[s*128 + 64 + d], sh = sinb[s*128 + 64 + d];
    t[base + d]      = lo_v * cl - hi_v * sl;
    t[base + 64 + d] = hi_v * ch + lo_v * sh;
}

// ---------------- block means: src [S][G][128] -> dst [C][G][128] ----------------
__global__ __launch_bounds__(256) void mean_blocks(
    const float* __restrict__ src, float* __restrict__ dst)
{
    int i = blockIdx.x * 256 + threadIdx.x;
    if (i >= NBLK * NG * DQK) return;
    int d = i & 127;
    int g = (i >> 7) & 1;
    int c = i >> 8;
    float s_ = 0.f;
    for (int j = 0; j < BLKSZ; j++)
        s_ += src[((size_t)(c*BLKSZ + j) * NG + g) * DQK + d];
    dst[i] = s_ * (1.f / 64.f);
}

// ---------------- kbuf f32 -> bf16 copy ----------------
__global__ __launch_bounds__(256) void kb_convert(
    const float* __restrict__ in, unsigned short* __restrict__ out, int n4)
{
    int i = blockIdx.x * 256 + threadIdx.x;
    if (i < n4){
        f32x4 v = ((const f32x4*)in)[i];
        ushort4 o;
        o.x = f2bf(v[0]); o.y = f2bf(v[1]); o.z = f2bf(v[2]); o.w = f2bf(v[3]);
        ((ushort4*)out)[i] = o;
    }
}

// ---------------- vbuf [S][G][128] f32 -> Vt [G][128][S] bf16 ----------------
__global__ __launch_bounds__(1024) void vt_transpose(
    const float* __restrict__ v, unsigned short* __restrict__ Vt)
{
    __shared__ float t[32][33];
    int g = blockIdx.z;
    int s0 = blockIdx.x * 32, d0 = blockIdx.y * 32;
    int tx = threadIdx.x, ty = threadIdx.y;
    t[ty][tx] = v[((size_t)(s0 + ty)*NG + g)*DQK + d0 + tx];
    __syncthreads();
    Vt[((size_t)g*DQK + d0 + ty)*S_LEN + s0 + tx] = f2bf(t[tx][ty]);
}

// ---------------- compressed attention + importance + topk (fp32, padded LDS) ----------------
__global__ __launch_bounds__(256) void cmp_attn(
    const float* __restrict__ q, const float* __restrict__ kc,
    const float* __restrict__ vc, const float* __restrict__ gates,
    float* __restrict__ o_acc, int* __restrict__ idxb)
{
    int s = blockIdx.x, g = blockIdx.y;
    __shared__ float qs[16][132];
    __shared__ float kcs[16][132];
    __shared__ float vcs[16][132];
    __shared__ float pcs[16][16];
    __shared__ float imps[16];
    int tid = threadIdx.x;
    for (int i = tid; i < 16*128; i += 256){
        int a = i >> 7, d = i & 127;
        qs[a][d]  = q[((size_t)s*NH + g*HPG + a)*DQK + d];
        kcs[a][d] = kc[((size_t)a*NG + g)*DQK + d];
        vcs[a][d] = vc[((size_t)a*NG + g)*DQK + d];
    }
    __syncthreads();
    int hh = tid >> 4, c = tid & 15;
    float acc = 0.f;
    for (int d4 = 0; d4 < 128; d4 += 4){
        f32x4 qv = *(const f32x4*)&qs[hh][d4];
        f32x4 kv = *(const f32x4*)&kcs[c][d4];
        acc += qv[0]*kv[0] + qv[1]*kv[1] + qv[2]*kv[2] + qv[3]*kv[3];
    }
    acc *= SCALE;
    bool vis = ((c + 1)*BLKSZ - 1) <= s;
    float l = vis ? acc : -1e30f;
    float m = l;
    #pragma unroll
    for (int off = 1; off < 16; off <<= 1) m = fmaxf(m, __shfl_xor(m, off));
    float p = vis ? __expf(l - m) : 0.f;
    float Z = p;
    #pragma unroll
    for (int off = 1; off < 16; off <<= 1) Z += __shfl_xor(Z, off);
    p = (Z > 0.f) ? (p / Z) : 0.f;
    pcs[hh][c] = p;
    __syncthreads();
    if (tid < 16){
        float si = 0.f;
        for (int a = 0; a < 16; a++) si += pcs[a][tid];
        imps[tid] = si;
    }
    __syncthreads();
    for (int i = tid; i < HPG*DQK; i += 256){
        int h2 = i >> 7, d = i & 127;
        float o = 0.f;
        #pragma unroll
        for (int cc = 0; cc < 16; cc++) o += pcs[h2][cc] * vcs[cc][d];
        int hf = g*HPG + h2;
        o_acc[((size_t)s*NH + hf)*DQK + d] = gates[((size_t)s*NH + hf)*3 + 0] * o;
    }
    if (tid == 0){
        int cur = s >> 6;
        float sc[16];
        #pragma unroll
        for (int c2 = 0; c2 < 16; c2++){
            bool valid = (c2*BLKSZ) <= s;
            bool force = (c2 == 0) || (c2 == cur);
            sc[c2] = (valid && force) ? 1e9f : (valid ? imps[c2] : -1e9f);
        }
        int base = (s*NG + g)*TOPN;
        #pragma unroll
        for (int n = 0; n < TOPN; n++){
            float bv = -1e38f; int bi = 0;
            for (int c2 = 0; c2 < 16; c2++) if (sc[c2] > bv){ bv = sc[c2]; bi = c2; }
            idxb[base + n] = bi;
            sc[bi] = -1e38f;
        }
    }
}

// ---------------- fused MFMA selected + window attention, LDS-staged ----------------
__global__ __launch_bounds__(256) void fused_attn(
    const float* __restrict__ q,            // [S][32][128] f32 (roped)
    const unsigned short* __restrict__ Kb,  // [S][2][128] bf16 (roped)
    const unsigned short* __restrict__ Vt,  // [2][128][S] bf16
    const float* __restrict__ gates,        // [S][32][3]
    const int* __restrict__ idxb,           // [S][2][4]
    const float* __restrict__ o_acc,        // [S][32][128] f32 (gated cmp)
    unsigned short* __restrict__ ob)        // [S][32][128] bf16
{
    const int s = blockIdx.x, g = blockIdx.y;
    const int tid = threadIdx.x;
    const int w = tid >> 6;
    const int lane = tid & 63;
    const int l15 = lane & 15;
    const int g4 = lane >> 4;
    __shared__ __align__(16) unsigned short K_lds[64*128];   // [key][d] xor-swizzled
    __shared__ __align__(16) unsigned short V_lds[128*64];   // [d][key] xor-swizzled
    __shared__ __align__(16) unsigned short P_lds[16][336];
    __shared__ float redm[4][16];
    __shared__ float reds[4][16];
    __shared__ int bidx[4];
    if (tid < 4) bidx[tid] = idxb[(s*NG + g)*TOPN + tid];

    // q fragments: B-operand rows = heads (l15), k over d
    bf16x8 qf[4];
    {
        const float* qrow = &q[((size_t)s*NH + g*HPG + l15)*DQK];
        #pragma unroll
        for (int ks = 0; ks < 4; ks++){
            int d0 = ks*32 + g4*8;
            f32x4 a = *(const f32x4*)(qrow + d0);
            f32x4 b = *(const f32x4*)(qrow + d0 + 4);
            bf16x8 r;
            #pragma unroll
            for (int i = 0; i < 4; i++){
                r[i]     = __builtin_bit_cast(__bf16, f2bf(a[i]));
                r[i + 4] = __builtin_bit_cast(__bf16, f2bf(b[i]));
            }
            qf[ks] = r;
        }
    }
    int wbase = (s >= 255) ? ((s - 255) & ~63) : 0;
    if (wbase > S_LEN - 320) wbase = S_LEN - 320;
    f32x4 oacc[2] = {};
    __syncthreads();   // bidx ready

    #pragma unroll
    for (int br = 0; br < 2; br++){
        const int nch = (br == 0) ? 4 : 5;       // 64-key chunks
        float sv[20];
        float mymax = -1e30f;
        // ---- QK over chunks ----
        for (int c = 0; c < nch; c++){
            int keybase = (br == 0) ? bidx[c]*64 : (wbase + c*64);
            // stage K[64][128] with inverse-swizzled source
            #pragma unroll
            for (int p = 0; p < 4; p++){
                int row = p*16 + (tid >> 4);
                int colb = ((tid & 15) << 4) ^ ((row & 7) << 4);
                const char* src = (const char*)Kb + (size_t)((keybase + row)*2 + g)*256 + colb;
                g2l16(src, (char*)K_lds + p*4096 + tid*16);
            }
            __syncthreads();
            // wave w computes keys [w*16, w*16+16) of this chunk
            f32x4 acc = {};
            {
                int r = w*16 + l15;
                const char* kb_ = (const char*)K_lds + r*256;
                int swz = (r & 7) << 4;
                #pragma unroll
                for (int ks2 = 0; ks2 < 4; ks2++){
                    bf16x8 kf = *(const bf16x8*)(kb_ + ((ks2*64 + g4*16) ^ swz));
                    acc = __builtin_amdgcn_mfma_f32_16x16x32_bf16(kf, qf[ks2], acc, 0, 0, 0);
                }
            }
            __syncthreads();   // all reads done before next stage
            #pragma unroll
            for (int j = 0; j < 4; j++){
                int pos = keybase + w*16 + g4*4 + j;
                float v = acc[j] * SCALE;
                bool ok = (pos <= s) && (br == 0 || pos + WIN > s);
                sv[c*4 + j] = ok ? v : -1e30f;
                mymax = fmaxf(mymax, sv[c*4 + j]);
            }
        }
        // prefetch V chunk 0 (latency hides under softmax)
        {
            int keybase = (br == 0) ? bidx[0]*64 : wbase;
            #pragma unroll
            for (int p = 0; p < 4; p++){
                int row = p*32 + (tid >> 3);
                int colb = ((tid & 7) << 4) ^ ((row & 7) << 4);
                const char* src = (const char*)Vt + ((size_t)(g*128 + row)*S_LEN + keybase)*2 + colb;
                g2l16(src, (char*)V_lds + p*4096 + tid*16);
            }
        }
        // ---- softmax (per head = l15) ----
        mymax = fmaxf(mymax, __shfl_xor(mymax, 16));
        mymax = fmaxf(mymax, __shfl_xor(mymax, 32));
        if (lane < 16) redm[w][lane] = mymax;
        __syncthreads();
        float gm = fmaxf(fmaxf(redm[0][l15], redm[1][l15]),
                         fmaxf(redm[2][l15], redm[3][l15]));
        float mysum = 0.f;
        #pragma unroll
        for (int c = 0; c < 5; c++) if (c < nch)
            #pragma unroll
            for (int j = 0; j < 4; j++){
                float e = (sv[c*4 + j] > -1e29f) ? __expf(sv[c*4 + j] - gm) : 0.f;
                sv[c*4 + j] = e;
                mysum += e;
            }
        mysum += __shfl_xor(mysum, 16);
        mysum += __shfl_xor(mysum, 32);
        if (lane < 16) reds[w][lane] = mysum;
        __syncthreads();
        float Z = reds[0][l15] + reds[1][l15] + reds[2][l15] + reds[3][l15];
        float gate = gates[((size_t)s*NH + g*HPG + l15)*3 + 1 + br];
        float fac = gate / Z;
        #pragma unroll
        for (int c = 0; c < 5; c++) if (c < nch)
            #pragma unroll
            for (int jp = 0; jp < 2; jp++){
                int key = c*64 + w*16 + g4*4 + jp*2;
                unsigned int pk = (unsigned int)f2bf(sv[c*4 + jp*2] * fac)
                                | ((unsigned int)f2bf(sv[c*4 + jp*2 + 1] * fac) << 16);
                *(unsigned int*)&P_lds[l15][key] = pk;
            }
        __syncthreads();   // P ready + V(0) staged (vmcnt drained by barrier)
        // ---- PV over chunks ----
        for (int c = 0; c < nch; c++){
            #pragma unroll
            for (int sub = 0; sub < 2; sub++){
                bf16x8 pf = *(const bf16x8*)&P_lds[l15][c*64 + sub*32 + g4*8];
                #pragma unroll
                for (int dt = 0; dt < 2; dt++){
                    int row = (2*w + dt)*16 + l15;
                    const char* vb = (const char*)V_lds + row*128
                                   + ((sub*64 + g4*16) ^ ((row & 7) << 4));
                    bf16x8 vf = *(const bf16x8*)vb;
                    oacc[dt] = __builtin_amdgcn_mfma_f32_16x16x32_bf16(pf, vf, oacc[dt], 0, 0, 0);
                }
            }
            __syncthreads();   // all reads of V_lds(c) done
            if (c + 1 < nch){
                int keybase = (br == 0) ? bidx[c+1]*64 : (wbase + (c+1)*64);
                #pragma unroll
                for (int p = 0; p < 4; p++){
                    int row = p*32 + (tid >> 3);
                    int colb = ((tid & 7) << 4) ^ ((row & 7) << 4);
                    const char* src = (const char*)Vt + ((size_t)(g*128 + row)*S_LEN + keybase)*2 + colb;
                    g2l16(src, (char*)V_lds + p*4096 + tid*16);
                }
                __syncthreads();   // V(c+1) staged
            }
        }
        __syncthreads();
    }
    #pragma unroll
    for (int dt = 0; dt < 2; dt++){
        int d = (2*w + dt)*16 + l15;
        #pragma unroll
        for (int j = 0; j < 4; j++){
            int h = g4*4 + j;
            size_t oo = ((size_t)s*NH + g*HPG + h)*DQK + d;
            ob[oo] = f2bf(o_acc[oo] + oacc[dt][j]);
        }
    }
}

extern "C" void kernel_launch(void* const* d_in, const int* in_sizes, int n_in,
                              void* d_out, int out_size, void* d_ws, size_t ws_size,
                              hipStream_t stream)
{
    (void)in_sizes; (void)n_in; (void)out_size; (void)ws_size;
    const float* x    = (const float*)d_in[0];
    const float* cosb = (const float*)d_in[1];
    const float* sinb = (const float*)d_in[2];
    const float* Wq   = (const float*)d_in[3];
    const float* Wk   = (const float*)d_in[4];
    const float* Wv   = (const float*)d_in[5];
    const float* Wo   = (const float*)d_in[6];
    const float* Wc   = (const float*)d_in[7];
    float* out = (float*)d_out;

    char* ws = (char*)d_ws;
    size_t off = 0;
    auto alloc = [&](size_t bytes)->char*{
        char* p = ws + off;
        off += (bytes + 255) & ~(size_t)255;
        return p;
    };
    unsigned short* WqT_hi = (unsigned short*)alloc(4096ull*2048*2); // later: partials, then o_acc
    unsigned short* WqT_lo = (unsigned short*)alloc(4096ull*2048*2); // later: WoT
    unsigned short* xb_hi  = (unsigned short*)alloc(1024ull*2048*2); // later: ob (spans hi+lo)
    unsigned short* xb_lo  = (unsigned short*)alloc(1024ull*2048*2);
    unsigned short* BcT_hi = (unsigned short*)alloc(640ull*2048*2);  // Wk|Wv|Wc hi; later Kbb
    unsigned short* BcT_lo = (unsigned short*)alloc(640ull*2048*2);  // Wk|Wv|Wc lo; later Vt
    float* qbuf  = (float*)alloc(1024ull*32*128*4);
    float* kbuf  = (float*)alloc(1024ull*2*128*4);
    float* vbuf  = (float*)alloc(1024ull*2*128*4);
    float* gbuf  = (float*)alloc(1024ull*96*4);
    float* kcb   = (float*)alloc(16ull*2*128*4);
    float* vcb   = (float*)alloc(16ull*2*128*4);
    int*   idxb  = (int*)alloc(1024ull*2*4*4);
    float* partials = (float*)WqT_hi;         // 4*1024*640*4 = 10.5MB <= 16MB
    float* o_acc = (float*)WqT_hi;            // after partials are reduced
    unsigned short* WoT = WqT_lo;             // after q GEMM
    unsigned short* ob  = xb_hi;              // after kvg GEMM
    unsigned short* Kbb = BcT_hi;             // after kvg GEMM
    unsigned short* Vt  = BcT_lo;             // after kvg GEMM

    // 1. split-convert x
    split_convert<<<dim3((1024*2048)/256), 256, 0, stream>>>(x, xb_hi, xb_lo, 1024*2048);
    // 2. transpose+convert weights (Wk|Wv|Wc into combined 640-row B, hi+lo)
    transpose_split<<<dim3(128, 64), dim3(32,32), 0, stream>>>(Wq, WqT_hi, WqT_lo, 2048, 4096);
    transpose_split<<<dim3(8, 64), dim3(32,32), 0, stream>>>(Wk, BcT_hi, BcT_lo, 2048, 256);
    transpose_split<<<dim3(8, 64), dim3(32,32), 0, stream>>>(Wv, BcT_hi + 256ull*2048, BcT_lo + 256ull*2048, 2048, 256);
    transpose_split<<<dim3(3, 64), dim3(32,32), 0, stream>>>(Wc, BcT_hi + 512ull*2048, BcT_lo + 512ull*2048, 2048, 96);
    // 3. q = x@Wq — fused split pass
    gemm_fused<3,0><<<dim3(64,8), 256, 0, stream>>>(xb_hi, xb_lo, WqT_hi, WqT_lo, qbuf, 1024, 4096, 2048);
    // 4. k|v|gates — one split-K=4 GEMM + deterministic reduce (sigmoid folded)
    gemm_fused<3,0><<<dim3(10,8,4), 256, 0, stream>>>(xb_hi, xb_lo, BcT_hi, BcT_lo, partials, 1024, 640, 2048);
    reduce_kvg<<<dim3(2432), 256, 0, stream>>>(partials, kbuf, vbuf, gbuf);
    // 5. Wo transpose (WqT_lo free)
    transpose_split<<<dim3(64, 128), dim3(32,32), 0, stream>>>(Wo, WoT, nullptr, 4096, 2048);
    // 6. RoPE in place
    rope_kernel<<<dim3((1024*32*64)/256), 256, 0, stream>>>(qbuf, cosb, sinb, 32, 1024*32*64);
    rope_kernel<<<dim3((1024*2*64)/256), 256, 0, stream>>>(kbuf, cosb, sinb, 2, 1024*2*64);
    // 7. block means
    mean_blocks<<<dim3(16), 256, 0, stream>>>(kbuf, kcb);
    mean_blocks<<<dim3(16), 256, 0, stream>>>(vbuf, vcb);
    // 8. bf16 copies for MFMA attention
    kb_convert<<<dim3((1024*2*128/4 + 255)/256), 256, 0, stream>>>(kbuf, Kbb, 1024*2*128/4);
    vt_transpose<<<dim3(1024/32, 128/32, 2), dim3(32,32), 0, stream>>>(vbuf, Vt);
    // 9. compressed attention -> gated o_acc + topk indices
    cmp_attn<<<dim3(1024,2), 256, 0, stream>>>(qbuf, kcb, vcb, gbuf, o_acc, idxb);
    // 10. fused MFMA selected+window attention -> final o (bf16)
    fused_attn<<<dim3(1024,2), 256, 0, stream>>>(qbuf, Kbb, Vt, gbuf, idxb, o_acc, ob);
    // 11. out = o @ Wo
    gemm_fused<1,0><<<dim3(32,8), 256, 0, stream>>>(ob, nullptr, WoT, nullptr, out, 1024, 2048, 4096);
}

// Round 6
// 344.226 us; speedup vs baseline: 3.1695x; 1.1243x over previous
//
#include <hip/hip_runtime.h>

#define S_LEN 1024
#define DMODEL 2048
#define NH 32
#define NG 2
#define HPG 16
#define DQK 128
#define NBLK 16
#define BLKSZ 64
#define TOPN 4
#define WIN 256
#define SCALE 0.08838834764831845f

typedef float f32x4 __attribute__((ext_vector_type(4)));
typedef __bf16 bf16x8 __attribute__((ext_vector_type(8)));

__device__ __forceinline__ unsigned short f2bf(float f){
    unsigned int u = __builtin_bit_cast(unsigned int, f);
    u += 0x7fffu + ((u >> 16) & 1u);
    return (unsigned short)(u >> 16);
}
__device__ __forceinline__ float bf2f(unsigned short h){
    unsigned int u = ((unsigned int)h) << 16;
    return __builtin_bit_cast(float, u);
}

using as1_u32 = __attribute__((address_space(1))) const unsigned int;
using as3_u32 = __attribute__((address_space(3))) unsigned int;
__device__ __forceinline__ void g2l16(const void* g, void* l){
    __builtin_amdgcn_global_load_lds((as1_u32*)g, (as3_u32*)l, 16, 0, 0);
}

// ---------------- split convert: x -> hi bf16, lo bf16 ----------------
__global__ __launch_bounds__(256) void split_convert(
    const float* __restrict__ in, unsigned short* __restrict__ hi,
    unsigned short* __restrict__ lo, int n)
{
    int i = blockIdx.x * 256 + threadIdx.x;
    if (i < n){
        float v = in[i];
        unsigned short h = f2bf(v);
        hi[i] = h;
        lo[i] = f2bf(v - bf2f(h));
    }
}

// ---------------- transpose W[K][N] -> WT[N][K] (bf16 hi, optional lo) ----------------
__global__ __launch_bounds__(1024) void transpose_split(
    const float* __restrict__ W, unsigned short* __restrict__ WT_hi,
    unsigned short* __restrict__ WT_lo, int K, int N)
{
    __shared__ float t[32][33];
    int tx = threadIdx.x, ty = threadIdx.y;
    int k0 = blockIdx.y * 32, n0 = blockIdx.x * 32;
    int nn = n0 + tx;
    float val = 0.f;
    if (nn < N) val = W[(size_t)(k0 + ty) * N + nn];
    t[ty][tx] = val;
    __syncthreads();
    int n2 = n0 + ty;
    if (n2 < N){
        float v2 = t[tx][ty];
        unsigned short h = f2bf(v2);
        WT_hi[(size_t)n2 * K + k0 + tx] = h;
        if (WT_lo){
            WT_lo[(size_t)n2 * K + k0 + tx] = f2bf(v2 - bf2f(h));
        }
    }
}

// ---- fused (optionally split-precision) MFMA GEMM, optional split-K via gridDim.z ----
// LDS is XOR-swizzled (T2): linear global_load_lds dest + inverse-swizzled global
// source col (ac ^ ((row&7)<<3) shorts) + same XOR on ds_read side.
template<int NTERM, int MODE>
__global__ __launch_bounds__(256) void gemm_fused(
    const unsigned short* __restrict__ Ah, const unsigned short* __restrict__ Al,
    const unsigned short* __restrict__ Bh, const unsigned short* __restrict__ Bl,
    float* __restrict__ Co, int M, int N, int K)
{
    __shared__ __align__(16) unsigned short smem[NTERM == 3 ? 24576 : 12288];
    unsigned short* As_h = smem;            // [128][64] swizzled
    unsigned short* Bs_h = smem + 8192;     // [64][64]
    unsigned short* As_l = smem + 12288;    // NTERM==3 only
    unsigned short* Bs_l = smem + 20480;

    // XCD-aware bijective block swizzle (x*y grids are %8==0)
    int gx = gridDim.x;
    int nwg = gx * gridDim.y;
    int bid = blockIdx.y * gx + blockIdx.x;
    int chunk = nwg >> 3;
    bid = (bid & 7) * chunk + (bid >> 3);
    const int n0 = (bid % gx) * 64;
    const int m0 = (bid / gx) * 128;

    const int kz = blockIdx.z;
    const int Kloc = K / gridDim.z;
    const int kbeg = kz * Kloc;
    Co += (size_t)kz * M * N;

    const int tid = threadIdx.x;
    const int lane = tid & 63;
    const int l15 = lane & 15;
    const int g4 = lane >> 4;
    const int w = tid >> 6;
    const int wr = w >> 1, wc = w & 1;
    const int ar = tid >> 3;            // staging row 0..31
    const int ac = (tid & 7) * 8;       // staging col (8 bf16 = 16B)
    const int acs = ac ^ ((ar & 7) << 3);   // inverse-swizzled source col
    const int rswz = (l15 & 7) << 3;        // read-side XOR (shorts)

    f32x4 acc[4][2] = {};

    for (int k0 = kbeg; k0 < kbeg + Kloc; k0 += 64){
        #pragma unroll
        for (int p = 0; p < 4; p++){
            int r = p*32 + ar;
            size_t go = (size_t)(m0 + r) * K + k0 + acs;
            int lo_ = p*2048 + tid*8;
            g2l16(Ah + go, As_h + lo_);
            if constexpr (NTERM == 3) g2l16(Al + go, As_l + lo_);
        }
        #pragma unroll
        for (int p = 0; p < 2; p++){
            int r = p*32 + ar;
            int nr = n0 + r; if (nr > N - 1) nr = N - 1;
            size_t go = (size_t)nr * K + k0 + acs;
            int lo_ = p*2048 + tid*8;
            g2l16(Bh + go, Bs_h + lo_);
            if constexpr (NTERM == 3) g2l16(Bl + go, Bs_l + lo_);
        }
        __syncthreads();
        #pragma unroll
        for (int ks = 0; ks < 2; ks++){
            const int kc_ = (ks*32 + g4*8) ^ rswz;
            bf16x8 ah[4], bh[2], al[4], bl[2];
            #pragma unroll
            for (int mi = 0; mi < 4; mi++){
                int row = wr*64 + mi*16 + l15;
                ah[mi] = *(const bf16x8*)&As_h[row*64 + kc_];
                if constexpr (NTERM == 3) al[mi] = *(const bf16x8*)&As_l[row*64 + kc_];
            }
            #pragma unroll
            for (int ni = 0; ni < 2; ni++){
                int row = wc*32 + ni*16 + l15;
                bh[ni] = *(const bf16x8*)&Bs_h[row*64 + kc_];
                if constexpr (NTERM == 3) bl[ni] = *(const bf16x8*)&Bs_l[row*64 + kc_];
            }
            #pragma unroll
            for (int mi = 0; mi < 4; mi++)
                #pragma unroll
                for (int ni = 0; ni < 2; ni++){
                    acc[mi][ni] = __builtin_amdgcn_mfma_f32_16x16x32_bf16(
                        ah[mi], bh[ni], acc[mi][ni], 0, 0, 0);
                    if constexpr (NTERM == 3){
                        acc[mi][ni] = __builtin_amdgcn_mfma_f32_16x16x32_bf16(
                            ah[mi], bl[ni], acc[mi][ni], 0, 0, 0);
                        acc[mi][ni] = __builtin_amdgcn_mfma_f32_16x16x32_bf16(
                            al[mi], bh[ni], acc[mi][ni], 0, 0, 0);
                    }
                }
        }
        __syncthreads();
    }
    #pragma unroll
    for (int mi = 0; mi < 4; mi++)
        #pragma unroll
        for (int ni = 0; ni < 2; ni++){
            int col = n0 + wc*32 + ni*16 + l15;
            if (col < N){
                int rbase = m0 + wr*64 + mi*16 + g4*4;
                #pragma unroll
                for (int j = 0; j < 4; j++){
                    float v = acc[mi][ni][j];
                    if (MODE == 1) v = 1.f / (1.f + __expf(-v));
                    Co[(size_t)(rbase + j) * N + col] = v;
                }
            }
        }
}

// ---------------- deterministic split-K reduce + routing (k | v | sigmoid gates) ----
__global__ __launch_bounds__(256) void reduce_kvg(
    const float* __restrict__ part, float* __restrict__ kbuf,
    float* __restrict__ vbuf, float* __restrict__ gbuf)
{
    int i = blockIdx.x * 256 + threadIdx.x;
    if (i >= 1024*608) return;
    int s = i / 608, c = i % 608;
    size_t o = (size_t)s * 640 + c;
    const size_t stride = 1024ull * 640;
    float sum = part[o] + part[o + stride] + part[o + 2*stride] + part[o + 3*stride];
    if (c < 256) kbuf[s*256 + c] = sum;
    else if (c < 512) vbuf[s*256 + (c - 256)] = sum;
    else gbuf[s*96 + (c - 512)] = 1.f / (1.f + __expf(-sum));
}

// ---------------- deterministic split-K=2 reduce into out (f32x4) ----------------
__global__ __launch_bounds__(256) void reduce_out(
    const float* __restrict__ part, float* __restrict__ out)
{
    int i = blockIdx.x * 256 + threadIdx.x;   // f32x4 index, n4 = 524288
    f32x4 a = ((const f32x4*)part)[i];
    f32x4 b = ((const f32x4*)part)[i + 524288];
    ((f32x4*)out)[i] = a + b;
}

// ---------------- RoPE (in place), t: [S][nh][128] ----------------
__global__ __launch_bounds__(256) void rope_kernel(
    float* __restrict__ t, const float* __restrict__ cosb,
    const float* __restrict__ sinb, int nh, int total)
{
    int i = blockIdx.x * 256 + threadIdx.x;
    if (i >= total) return;
    int d = i & 63;
    int r = i >> 6;
    int s = r / nh;
    size_t base = (size_t)r * 128;
    float lo_v = t[base + d], hi_v = t[base + 64 + d];
    float cl = cosb[s*128 + d],      sl = sinb[s*128 + d];
    float ch = cosb[s*128 + 64 + d], sh = sinb[s*128 + 64 + d];
    t[base + d]      = lo_v * cl - hi_v * sl;
    t[base + 64 + d] = hi_v * ch + lo_v * sh;
}

// ---------------- RoPE for k (in place) + bf16 copy out ----------------
__global__ __launch_bounds__(256) void rope_k_kernel(
    float* __restrict__ t, const float* __restrict__ cosb,
    const float* __restrict__ sinb, unsigned short* __restrict__ kb)
{
    int i = blockIdx.x * 256 + threadIdx.x;
    if (i >= 1024*2*64) return;
    int d = i & 63;
    int r = i >> 6;           // s*2 + g
    int s = r >> 1;
    size_t base = (size_t)r * 128;
    float lo_v = t[base + d], hi_v = t[base + 64 + d];
    float cl = cosb[s*128 + d],      sl = sinb[s*128 + d];
    float ch = cosb[s*128 + 64 + d], sh = sinb[s*128 + 64 + d];
    float nl = lo_v * cl - hi_v * sl;
    float nh = hi_v * ch + lo_v * sh;
    t[base + d]      = nl;
    t[base + 64 + d] = nh;
    kb[base + d]      = f2bf(nl);
    kb[base + 64 + d] = f2bf(nh);
}

// ---------------- block means for k and v in one launch ----------------
__global__ __launch_bounds__(256) void mean_blocks2(
    const float* __restrict__ ksrc, const float* __restrict__ vsrc,
    float* __restrict__ kc, float* __restrict__ vc)
{
    int i = blockIdx.x * 256 + threadIdx.x;
    if (i >= 2*NBLK*NG*DQK) return;
    const float* src = (i < NBLK*NG*DQK) ? ksrc : vsrc;
    float* dst = (i < NBLK*NG*DQK) ? kc : vc;
    int j = i & (NBLK*NG*DQK - 1);
    int d = j & 127;
    int g = (j >> 7) & 1;
    int c = j >> 8;
    float s_ = 0.f;
    for (int jj = 0; jj < BLKSZ; jj++)
        s_ += src[((size_t)(c*BLKSZ + jj) * NG + g) * DQK + d];
    dst[j] = s_ * (1.f / 64.f);
}

// ---------------- vbuf [S][G][128] f32 -> Vt [G][128][S] bf16 ----------------
__global__ __launch_bounds__(1024) void vt_transpose(
    const float* __restrict__ v, unsigned short* __restrict__ Vt)
{
    __shared__ float t[32][33];
    int g = blockIdx.z;
    int s0 = blockIdx.x * 32, d0 = blockIdx.y * 32;
    int tx = threadIdx.x, ty = threadIdx.y;
    t[ty][tx] = v[((size_t)(s0 + ty)*NG + g)*DQK + d0 + tx];
    __syncthreads();
    Vt[((size_t)g*DQK + d0 + ty)*S_LEN + s0 + tx] = f2bf(t[tx][ty]);
}

// ---------------- compressed attention + importance + topk (fp32, padded LDS) ----------------
__global__ __launch_bounds__(256) void cmp_attn(
    const float* __restrict__ q, const float* __restrict__ kc,
    const float* __restrict__ vc, const float* __restrict__ gates,
    float* __restrict__ o_acc, int* __restrict__ idxb)
{
    int s = blockIdx.x, g = blockIdx.y;
    __shared__ float qs[16][132];
    __shared__ float kcs[16][132];
    __shared__ float vcs[16][132];
    __shared__ float pcs[16][16];
    __shared__ float imps[16];
    int tid = threadIdx.x;
    for (int i = tid; i < 16*128; i += 256){
        int a = i >> 7, d = i & 127;
        qs[a][d]  = q[((size_t)s*NH + g*HPG + a)*DQK + d];
        kcs[a][d] = kc[((size_t)a*NG + g)*DQK + d];
        vcs[a][d] = vc[((size_t)a*NG + g)*DQK + d];
    }
    __syncthreads();
    int hh = tid >> 4, c = tid & 15;
    float acc = 0.f;
    for (int d4 = 0; d4 < 128; d4 += 4){
        f32x4 qv = *(const f32x4*)&qs[hh][d4];
        f32x4 kv = *(const f32x4*)&kcs[c][d4];
        acc += qv[0]*kv[0] + qv[1]*kv[1] + qv[2]*kv[2] + qv[3]*kv[3];
    }
    acc *= SCALE;
    bool vis = ((c + 1)*BLKSZ - 1) <= s;
    float l = vis ? acc : -1e30f;
    float m = l;
    #pragma unroll
    for (int off = 1; off < 16; off <<= 1) m = fmaxf(m, __shfl_xor(m, off));
    float p = vis ? __expf(l - m) : 0.f;
    float Z = p;
    #pragma unroll
    for (int off = 1; off < 16; off <<= 1) Z += __shfl_xor(Z, off);
    p = (Z > 0.f) ? (p / Z) : 0.f;
    pcs[hh][c] = p;
    __syncthreads();
    if (tid < 16){
        float si = 0.f;
        for (int a = 0; a < 16; a++) si += pcs[a][tid];
        imps[tid] = si;
    }
    __syncthreads();
    for (int i = tid; i < HPG*DQK; i += 256){
        int h2 = i >> 7, d = i & 127;
        float o = 0.f;
        #pragma unroll
        for (int cc = 0; cc < 16; cc++) o += pcs[h2][cc] * vcs[cc][d];
        int hf = g*HPG + h2;
        o_acc[((size_t)s*NH + hf)*DQK + d] = gates[((size_t)s*NH + hf)*3 + 0] * o;
    }
    if (tid == 0){
        int cur = s >> 6;
        float sc[16];
        #pragma unroll
        for (int c2 = 0; c2 < 16; c2++){
            bool valid = (c2*BLKSZ) <= s;
            bool force = (c2 == 0) || (c2 == cur);
            sc[c2] = (valid && force) ? 1e9f : (valid ? imps[c2] : -1e9f);
        }
        int base = (s*NG + g)*TOPN;
        #pragma unroll
        for (int n = 0; n < TOPN; n++){
            float bv = -1e38f; int bi = 0;
            for (int c2 = 0; c2 < 16; c2++) if (sc[c2] > bv){ bv = sc[c2]; bi = c2; }
            idxb[base + n] = bi;
            sc[bi] = -1e38f;
        }
    }
}

// ---------------- fused MFMA selected + window attention, LDS-staged ----------------
__global__ __launch_bounds__(256) void fused_attn(
    const float* __restrict__ q,            // [S][32][128] f32 (roped)
    const unsigned short* __restrict__ Kb,  // [S][2][128] bf16 (roped)
    const unsigned short* __restrict__ Vt,  // [2][128][S] bf16
    const float* __restrict__ gates,        // [S][32][3]
    const int* __restrict__ idxb,           // [S][2][4]
    const float* __restrict__ o_acc,        // [S][32][128] f32 (gated cmp)
    unsigned short* __restrict__ ob)        // [S][32][128] bf16
{
    const int s = blockIdx.x, g = blockIdx.y;
    const int tid = threadIdx.x;
    const int w = tid >> 6;
    const int lane = tid & 63;
    const int l15 = lane & 15;
    const int g4 = lane >> 4;
    __shared__ __align__(16) unsigned short K_lds[64*128];   // [key][d] xor-swizzled
    __shared__ __align__(16) unsigned short V_lds[128*64];   // [d][key] xor-swizzled
    __shared__ __align__(16) unsigned short P_lds[16][340];
    __shared__ float redm[4][16];
    __shared__ float reds[4][16];
    __shared__ int bidx[4];
    if (tid < 4) bidx[tid] = idxb[(s*NG + g)*TOPN + tid];

    bf16x8 qf[4];
    {
        const float* qrow = &q[((size_t)s*NH + g*HPG + l15)*DQK];
        #pragma unroll
        for (int ks = 0; ks < 4; ks++){
            int d0 = ks*32 + g4*8;
            f32x4 a = *(const f32x4*)(qrow + d0);
            f32x4 b = *(const f32x4*)(qrow + d0 + 4);
            bf16x8 r;
            #pragma unroll
            for (int i = 0; i < 4; i++){
                r[i]     = __builtin_bit_cast(__bf16, f2bf(a[i]));
                r[i + 4] = __builtin_bit_cast(__bf16, f2bf(b[i]));
            }
            qf[ks] = r;
        }
    }
    int wbase = (s >= 255) ? ((s - 255) & ~63) : 0;
    if (wbase > S_LEN - 320) wbase = S_LEN - 320;
    f32x4 oacc[2] = {};
    __syncthreads();   // bidx ready

    #pragma unroll
    for (int br = 0; br < 2; br++){
        const int nch = (br == 0) ? 4 : 5;       // 64-key chunks
        float sv[20];
        float mymax = -1e30f;
        // ---- QK over chunks ----
        for (int c = 0; c < nch; c++){
            int keybase = (br == 0) ? bidx[c]*64 : (wbase + c*64);
            #pragma unroll
            for (int p = 0; p < 4; p++){
                int row = p*16 + (tid >> 4);
                int colb = ((tid & 15) << 4) ^ ((row & 7) << 4);
                const char* src = (const char*)Kb + (size_t)((keybase + row)*2 + g)*256 + colb;
                g2l16(src, (char*)K_lds + p*4096 + tid*16);
            }
            __syncthreads();
            f32x4 acc = {};
            {
                int r = w*16 + l15;
                const char* kb_ = (const char*)K_lds + r*256;
                int swz = (r & 7) << 4;
                #pragma unroll
                for (int ks2 = 0; ks2 < 4; ks2++){
                    bf16x8 kf = *(const bf16x8*)(kb_ + ((ks2*64 + g4*16) ^ swz));
                    acc = __builtin_amdgcn_mfma_f32_16x16x32_bf16(kf, qf[ks2], acc, 0, 0, 0);
                }
            }
            __syncthreads();
            #pragma unroll
            for (int j = 0; j < 4; j++){
                int pos = keybase + w*16 + g4*4 + j;
                float v = acc[j] * SCALE;
                bool ok = (pos <= s) && (br == 0 || pos + WIN > s);
                sv[c*4 + j] = ok ? v : -1e30f;
                mymax = fmaxf(mymax, sv[c*4 + j]);
            }
        }
        // prefetch V chunk 0
        {
            int keybase = (br == 0) ? bidx[0]*64 : wbase;
            #pragma unroll
            for (int p = 0; p < 4; p++){
                int row = p*32 + (tid >> 3);
                int colb = ((tid & 7) << 4) ^ ((row & 7) << 4);
                const char* src = (const char*)Vt + ((size_t)(g*128 + row)*S_LEN + keybase)*2 + colb;
                g2l16(src, (char*)V_lds + p*4096 + tid*16);
            }
        }
        // ---- softmax ----
        mymax = fmaxf(mymax, __shfl_xor(mymax, 16));
        mymax = fmaxf(mymax, __shfl_xor(mymax, 32));
        if (lane < 16) redm[w][lane] = mymax;
        __syncthreads();
        float gm = fmaxf(fmaxf(redm[0][l15], redm[1][l15]),
                         fmaxf(redm[2][l15], redm[3][l15]));
        float mysum = 0.f;
        #pragma unroll
        for (int c = 0; c < 5; c++) if (c < nch)
            #pragma unroll
            for (int j = 0; j < 4; j++){
                float e = (sv[c*4 + j] > -1e29f) ? __expf(sv[c*4 + j] - gm) : 0.f;
                sv[c*4 + j] = e;
                mysum += e;
            }
        mysum += __shfl_xor(mysum, 16);
        mysum += __shfl_xor(mysum, 32);
        if (lane < 16) reds[w][lane] = mysum;
        __syncthreads();
        float Z = reds[0][l15] + reds[1][l15] + reds[2][l15] + reds[3][l15];
        float gate = gates[((size_t)s*NH + g*HPG + l15)*3 + 1 + br];
        float fac = gate / Z;
        #pragma unroll
        for (int c = 0; c < 5; c++) if (c < nch)
            #pragma unroll
            for (int jp = 0; jp < 2; jp++){
                int key = c*64 + w*16 + g4*4 + jp*2;
                unsigned int pk = (unsigned int)f2bf(sv[c*4 + jp*2] * fac)
                                | ((unsigned int)f2bf(sv[c*4 + jp*2 + 1] * fac) << 16);
                *(unsigned int*)&P_lds[l15][key] = pk;
            }
        __syncthreads();   // P ready + V(0) staged
        // ---- PV over chunks ----
        for (int c = 0; c < nch; c++){
            #pragma unroll
            for (int sub = 0; sub < 2; sub++){
                bf16x8 pf = *(const bf16x8*)&P_lds[l15][c*64 + sub*32 + g4*8];
                #pragma unroll
                for (int dt = 0; dt < 2; dt++){
                    int row = (2*w + dt)*16 + l15;
                    const char* vb = (const char*)V_lds + row*128
                                   + ((sub*64 + g4*16) ^ ((row & 7) << 4));
                    bf16x8 vf = *(const bf16x8*)vb;
                    oacc[dt] = __builtin_amdgcn_mfma_f32_16x16x32_bf16(pf, vf, oacc[dt], 0, 0, 0);
                }
            }
            __syncthreads();
            if (c + 1 < nch){
                int keybase = (br == 0) ? bidx[c+1]*64 : (wbase + (c+1)*64);
                #pragma unroll
                for (int p = 0; p < 4; p++){
                    int row = p*32 + (tid >> 3);
                    int colb = ((tid & 7) << 4) ^ ((row & 7) << 4);
                    const char* src = (const char*)Vt + ((size_t)(g*128 + row)*S_LEN + keybase)*2 + colb;
                    g2l16(src, (char*)V_lds + p*4096 + tid*16);
                }
                __syncthreads();
            }
        }
        __syncthreads();
    }
    #pragma unroll
    for (int dt = 0; dt < 2; dt++){
        int d = (2*w + dt)*16 + l15;
        #pragma unroll
        for (int j = 0; j < 4; j++){
            int h = g4*4 + j;
            size_t oo = ((size_t)s*NH + g*HPG + h)*DQK + d;
            ob[oo] = f2bf(o_acc[oo] + oacc[dt][j]);
        }
    }
}

extern "C" void kernel_launch(void* const* d_in, const int* in_sizes, int n_in,
                              void* d_out, int out_size, void* d_ws, size_t ws_size,
                              hipStream_t stream)
{
    (void)in_sizes; (void)n_in; (void)out_size; (void)ws_size;
    const float* x    = (const float*)d_in[0];
    const float* cosb = (const float*)d_in[1];
    const float* sinb = (const float*)d_in[2];
    const float* Wq   = (const float*)d_in[3];
    const float* Wk   = (const float*)d_in[4];
    const float* Wv   = (const float*)d_in[5];
    const float* Wo   = (const float*)d_in[6];
    const float* Wc   = (const float*)d_in[7];
    float* out = (float*)d_out;

    char* ws = (char*)d_ws;
    size_t off = 0;
    auto alloc = [&](size_t bytes)->char*{
        char* p = ws + off;
        off += (bytes + 255) & ~(size_t)255;
        return p;
    };
    unsigned short* WqT_hi = (unsigned short*)alloc(4096ull*2048*2); // later: kvg partials -> o_acc -> Wo partials
    unsigned short* WqT_lo = (unsigned short*)alloc(4096ull*2048*2); // later: WoT
    unsigned short* xb_hi  = (unsigned short*)alloc(1024ull*2048*2); // later: ob (spans hi+lo)
    unsigned short* xb_lo  = (unsigned short*)alloc(1024ull*2048*2);
    unsigned short* BcT_hi = (unsigned short*)alloc(640ull*2048*2);  // Wk|Wv|Wc hi; later Kbb
    unsigned short* BcT_lo = (unsigned short*)alloc(640ull*2048*2);  // Wk|Wv|Wc lo; later Vt
    float* qbuf  = (float*)alloc(1024ull*32*128*4);
    float* kbuf  = (float*)alloc(1024ull*2*128*4);
    float* vbuf  = (float*)alloc(1024ull*2*128*4);
    float* gbuf  = (float*)alloc(1024ull*96*4);
    float* kcb   = (float*)alloc(16ull*2*128*4);
    float* vcb   = (float*)alloc(16ull*2*128*4);
    int*   idxb  = (int*)alloc(1024ull*2*4*4);
    float* partials = (float*)WqT_hi;         // kvg: 4*1024*640*4 = 10.5MB
    float* o_acc = (float*)WqT_hi;            // after kvg partials reduced
    float* wo_part = (float*)WqT_hi;          // after o_acc consumed: 2*1024*2048*4 = 16.78MB (fits exactly)
    unsigned short* WoT = WqT_lo;             // after q GEMM
    unsigned short* ob  = xb_hi;              // after projection GEMMs
    unsigned short* Kbb = BcT_hi;             // after kvg GEMM
    unsigned short* Vt  = BcT_lo;             // after kvg GEMM

    // 1. split-convert x
    split_convert<<<dim3((1024*2048)/256), 256, 0, stream>>>(x, xb_hi, xb_lo, 1024*2048);
    // 2. transpose+convert weights (Wk|Wv|Wc combined)
    transpose_split<<<dim3(128, 64), dim3(32,32), 0, stream>>>(Wq, WqT_hi, WqT_lo, 2048, 4096);
    transpose_split<<<dim3(8, 64), dim3(32,32), 0, stream>>>(Wk, BcT_hi, BcT_lo, 2048, 256);
    transpose_split<<<dim3(8, 64), dim3(32,32), 0, stream>>>(Wv, BcT_hi + 256ull*2048, BcT_lo + 256ull*2048, 2048, 256);
    transpose_split<<<dim3(3, 64), dim3(32,32), 0, stream>>>(Wc, BcT_hi + 512ull*2048, BcT_lo + 512ull*2048, 2048, 96);
    // 3. q = x@Wq — fused split pass
    gemm_fused<3,0><<<dim3(64,8), 256, 0, stream>>>(xb_hi, xb_lo, WqT_hi, WqT_lo, qbuf, 1024, 4096, 2048);
    // 4. k|v|gates — split-K=4 GEMM + deterministic reduce (sigmoid folded)
    gemm_fused<3,0><<<dim3(10,8,4), 256, 0, stream>>>(xb_hi, xb_lo, BcT_hi, BcT_lo, partials, 1024, 640, 2048);
    reduce_kvg<<<dim3(2432), 256, 0, stream>>>(partials, kbuf, vbuf, gbuf);
    // 5. Wo transpose (WqT_lo free)
    transpose_split<<<dim3(64, 128), dim3(32,32), 0, stream>>>(Wo, WoT, nullptr, 4096, 2048);
    // 6. RoPE (k pass also emits bf16 Kbb)
    rope_kernel<<<dim3((1024*32*64)/256), 256, 0, stream>>>(qbuf, cosb, sinb, 32, 1024*32*64);
    rope_k_kernel<<<dim3((1024*2*64)/256), 256, 0, stream>>>(kbuf, cosb, sinb, Kbb);
    // 7. block means (k + v in one launch)
    mean_blocks2<<<dim3(32), 256, 0, stream>>>(kbuf, vbuf, kcb, vcb);
    // 8. V transpose to Vt bf16
    vt_transpose<<<dim3(1024/32, 128/32, 2), dim3(32,32), 0, stream>>>(vbuf, Vt);
    // 9. compressed attention -> gated o_acc + topk indices
    cmp_attn<<<dim3(1024,2), 256, 0, stream>>>(qbuf, kcb, vcb, gbuf, o_acc, idxb);
    // 10. fused MFMA selected+window attention -> final o (bf16)
    fused_attn<<<dim3(1024,2), 256, 0, stream>>>(qbuf, Kbb, Vt, gbuf, idxb, o_acc, ob);
    // 11. out = o @ Wo — split-K=2 + deterministic reduce
    gemm_fused<1,0><<<dim3(32,8,2), 256, 0, stream>>>(ob, nullptr, WoT, nullptr, wo_part, 1024, 2048, 4096);
    reduce_out<<<dim3(2048), 256, 0, stream>>>(wo_part, out);
}